// Round 1
// baseline (706.942 us; speedup 1.0000x reference)
//
#include <hip/hip_runtime.h>
#include <cstddef>

#define NPTS 8192
#define DIM  128

// K1 tiling: 32 rows x 64 cols per LDS tile, 8 column splits for parallelism.
#define RB      32
#define CT      64
#define SPLITS  8
#define CPB     (NPTS / SPLITS)   // 1024 cols per block
#define NTILES  (CPB / CT)        // 16
#define PADS    132               // padded LDS stride (floats): float4-aligned, conflict-light

__device__ __forceinline__ void insert6(float d, int idx, float bd[6], int bi[6]) {
    // bd sorted ascending; replace worst then bubble (static indices only).
    if (d < bd[5]) {
        bd[5] = d; bi[5] = idx;
#pragma unroll
        for (int q = 5; q >= 1; --q) {
            if (bd[q] < bd[q - 1]) {
                float td = bd[q]; bd[q] = bd[q - 1]; bd[q - 1] = td;
                int   ti = bi[q]; bi[q] = bi[q - 1]; bi[q - 1] = ti;
            }
        }
    }
}

// K1: per (row-block, col-split): compute d2 for 32 rows x 1024 cols, keep
// per-row top-6 (d2, idx); write partials into the first 96 floats of each
// output row (d_out is scratch until K2 rewrites every row).
__global__ __launch_bounds__(256) void knn_partial(const float* __restrict__ F,
                                                   float* __restrict__ out) {
    __shared__ float rowF[RB * PADS];   // 16896 B
    __shared__ float colF[CT * PADS];   // 33792 B
    __shared__ float sqr[RB];
    __shared__ float sqc[CT];

    const int tid  = threadIdx.x;
    const int bx   = blockIdx.x;
    const int rb   = bx & ((NPTS / RB) - 1);   // 0..255
    const int cs   = bx >> 8;                  // 0..7
    const int row0 = rb * RB;
    const int col0 = cs * CPB;

    // stage row tile (32x128 floats = 1024 float4, 4 per thread), coalesced
#pragma unroll
    for (int m = 0; m < 4; ++m) {
        int flat = m * 256 + tid;
        int r  = flat >> 5;
        int kq = flat & 31;
        float4 v = *(const float4*)&F[(size_t)(row0 + r) * DIM + kq * 4];
        *(float4*)&rowF[r * PADS + kq * 4] = v;
    }
    __syncthreads();
    if (tid < RB) {
        float s = 0.f;
#pragma unroll
        for (int kq = 0; kq < 32; ++kq) {
            float4 v = *(const float4*)&rowF[tid * PADS + kq * 4];
            s += v.x * v.x + v.y * v.y + v.z * v.z + v.w * v.w;
        }
        sqr[tid] = s;
    }

    // micro-tile: rows r = (tid>>4) + 16*i (i<2), cols c = (tid&15) + 16*j (j<4)
    const int rl = tid >> 4;
    const int cl = tid & 15;

    float bd[2][6];
    int   bi[2][6];
#pragma unroll
    for (int i = 0; i < 2; ++i)
#pragma unroll
        for (int q = 0; q < 6; ++q) { bd[i][q] = 3.0e38f; bi[i][q] = 0; }

    for (int t = 0; t < NTILES; ++t) {
        const int cbase = col0 + t * CT;
        __syncthreads();   // protect colF/sqc from previous-iteration readers
        // stage col tile (64x128 floats = 2048 float4, 8 per thread)
#pragma unroll
        for (int m = 0; m < 8; ++m) {
            int flat = m * 256 + tid;
            int c  = flat >> 5;
            int kq = flat & 31;
            float4 v = *(const float4*)&F[(size_t)(cbase + c) * DIM + kq * 4];
            *(float4*)&colF[c * PADS + kq * 4] = v;
        }
        __syncthreads();
        if (tid < CT) {
            float s = 0.f;
#pragma unroll
            for (int kq = 0; kq < 32; ++kq) {
                float4 v = *(const float4*)&colF[tid * PADS + kq * 4];
                s += v.x * v.x + v.y * v.y + v.z * v.z + v.w * v.w;
            }
            sqc[tid] = s;
        }
        __syncthreads();

        float acc[2][4];
#pragma unroll
        for (int i = 0; i < 2; ++i)
#pragma unroll
            for (int j = 0; j < 4; ++j) acc[i][j] = 0.f;

#pragma unroll 4
        for (int kq = 0; kq < 32; ++kq) {
            float4 a[2], b[4];
#pragma unroll
            for (int i = 0; i < 2; ++i)
                a[i] = *(const float4*)&rowF[(rl + 16 * i) * PADS + kq * 4];
#pragma unroll
            for (int j = 0; j < 4; ++j)
                b[j] = *(const float4*)&colF[(cl + 16 * j) * PADS + kq * 4];
#pragma unroll
            for (int i = 0; i < 2; ++i)
#pragma unroll
                for (int j = 0; j < 4; ++j) {
                    acc[i][j] = fmaf(a[i].x, b[j].x, acc[i][j]);
                    acc[i][j] = fmaf(a[i].y, b[j].y, acc[i][j]);
                    acc[i][j] = fmaf(a[i].z, b[j].z, acc[i][j]);
                    acc[i][j] = fmaf(a[i].w, b[j].w, acc[i][j]);
                }
        }

        // epilogue: d2 + top-6 insert (selection on d2; sqrt deferred to K2)
#pragma unroll
        for (int i = 0; i < 2; ++i) {
            const int r  = rl + 16 * i;
            const int gr = row0 + r;
#pragma unroll
            for (int j = 0; j < 4; ++j) {
                const int c  = cl + 16 * j;
                const int gc = cbase + c;
                float d2 = sqr[r] + sqc[c] - 2.0f * acc[i][j];
                d2 = (gr == gc) ? 1e-30f : fmaxf(d2, 1e-30f);
                insert6(d2, gc, bd[i], bi[i]);
            }
        }
    }

    // block-level merge: dump per-thread candidates to LDS (reuse tiles)
    __syncthreads();
    float* cd = colF;   // 32*16*6 = 3072 floats <= 8448
    float* ci = rowF;   // 3072 floats <= 4224
#pragma unroll
    for (int i = 0; i < 2; ++i) {
        const int r = rl + 16 * i;
#pragma unroll
        for (int q = 0; q < 6; ++q) {
            cd[(r * 16 + cl) * 6 + q] = bd[i][q];
            ci[(r * 16 + cl) * 6 + q] = __int_as_float(bi[i][q]);
        }
    }
    __syncthreads();
    if (tid < RB) {
        float md[6]; int mi[6];
#pragma unroll
        for (int q = 0; q < 6; ++q) { md[q] = 3.0e38f; mi[q] = 0; }
        for (int g = 0; g < 16; ++g) {
#pragma unroll
            for (int q = 0; q < 6; ++q) {
                float d2 = cd[(tid * 16 + g) * 6 + q];
                int   ix = __float_as_int(ci[(tid * 16 + g) * 6 + q]);
                insert6(d2, ix, md, mi);
            }
        }
        // partial slot: 12 floats per split at the head of the output row
        float* dst = &out[(size_t)(row0 + tid) * NPTS + cs * 12];
#pragma unroll
        for (int q = 0; q < 6; ++q) {
            dst[q]     = md[q];
            dst[6 + q] = __int_as_float(mi[q]);
        }
    }
}

// K2: one block per row — merge the 8 partial top-6 lists, compute T / weights /
// norm, zero the row, scatter the 6 normalized weights.
__global__ __launch_bounds__(256) void knn_finalize(float* __restrict__ out) {
    __shared__ float pbuf[SPLITS * 12];
    __shared__ float w_s[6];
    __shared__ int   wi_s[6];

    const int    tid  = threadIdx.x;
    const size_t base = (size_t)blockIdx.x * NPTS;

    if (tid < SPLITS * 12) pbuf[tid] = out[base + tid];
    __syncthreads();

    if (tid == 0) {
        float md[6]; int mi[6];
#pragma unroll
        for (int q = 0; q < 6; ++q) { md[q] = 3.0e38f; mi[q] = 0; }
        for (int s = 0; s < SPLITS; ++s) {
#pragma unroll
            for (int q = 0; q < 6; ++q) {
                float d2 = pbuf[s * 12 + q];
                int   ix = __float_as_int(pbuf[s * 12 + 6 + q]);
                insert6(d2, ix, md, mi);
            }
        }
        const float T = sqrtf(md[5]);   // 6th-smallest distance
        float w[6];
        float norm = 0.f;
#pragma unroll
        for (int q = 0; q < 6; ++q) {
            w[q] = T - sqrtf(md[q]) + 1e-10f;
            norm += w[q];
        }
        const float inv = 1.0f / fmaxf(norm, 1e-12f);
#pragma unroll
        for (int q = 0; q < 6; ++q) { w_s[q] = w[q] * inv; wi_s[q] = mi[q]; }
    }
    __syncthreads();

    // zero the whole row (8192 floats = 8 float4 per thread)
#pragma unroll
    for (int m = 0; m < 8; ++m)
        *(float4*)&out[base + (size_t)(m * 256 + tid) * 4] = make_float4(0.f, 0.f, 0.f, 0.f);
    __syncthreads();

    if (tid < 6) out[base + wi_s[tid]] = w_s[tid];
}

extern "C" void kernel_launch(void* const* d_in, const int* in_sizes, int n_in,
                              void* d_out, int out_size, void* d_ws, size_t ws_size,
                              hipStream_t stream) {
    const float* F   = (const float*)d_in[0];
    float*       out = (float*)d_out;
    knn_partial<<<dim3((NPTS / RB) * SPLITS), dim3(256), 0, stream>>>(F, out);
    knn_finalize<<<dim3(NPTS), dim3(256), 0, stream>>>(out);
}

// Round 2
// 557.395 us; speedup vs baseline: 1.2683x; 1.2683x over previous
//
#include <hip/hip_runtime.h>
#include <cstddef>
#include <cstdint>

#define NPTS 8192
#define DIM  128

// ------------------------- new MFMA path constants -------------------------
#define K3      384            // [hi|hi|lo] . [hi|lo|hi]
#define BK      64             // k per staging iter = 8 chunks of 8 bf16
#define KITERS  (K3 / BK)      // 6
#define BM      128
#define BN      128
#define NSPLIT  8
#define CPB2    (NPTS / NSPLIT)  // 1024 cols per block
#define NT2     (CPB2 / BN)      // 8 col tiles
#define EPI_STRIDE 133           // 64 x 133 fp32 epilogue buffer (bank-spread)

using bf16x8 = __attribute__((ext_vector_type(8))) short;
using f32x4  = __attribute__((ext_vector_type(4))) float;

// ws layout (bytes)
#define WS_A    ((size_t)0)
#define WS_B    ((size_t)NPTS * K3 * 2)             // 6 MB
#define WS_SQ   ((size_t)2 * NPTS * K3 * 2)         // 12 MB
#define WS_PART (WS_SQ + (size_t)NPTS * 4)          // +32 KB
#define WS_NEED (WS_PART + (size_t)NPTS * 96 * 4)   // +3 MB = 15761408 B

__device__ __forceinline__ void insert6(float d, int idx, float bd[6], int bi[6]) {
    if (d < bd[5]) {
        bd[5] = d; bi[5] = idx;
#pragma unroll
        for (int q = 5; q >= 1; --q) {
            if (bd[q] < bd[q - 1]) {
                float td = bd[q]; bd[q] = bd[q - 1]; bd[q - 1] = td;
                int   ti = bi[q]; bi[q] = bi[q - 1]; bi[q - 1] = ti;
            }
        }
    }
}

__device__ __forceinline__ void async16(const void* g, void* l) {
    __builtin_amdgcn_global_load_lds(
        (const __attribute__((address_space(1))) void*)g,
        (__attribute__((address_space(3))) void*)l,
        16, 0, 0);
}

// K0: fp32 -> split bf16 (hi, lo); build A' = [hi|hi|lo], B' = [hi|lo|hi]; sq.
__global__ __launch_bounds__(128) void prep(const float* __restrict__ F,
                                            short* __restrict__ A,
                                            short* __restrict__ B,
                                            float* __restrict__ sq) {
    __shared__ float red[128];
    const int p = blockIdx.x;
    const int t = threadIdx.x;
    float f = F[(size_t)p * DIM + t];
    uint32_t u  = __float_as_uint(f);
    uint32_t hb = (u + 0x7fffu + ((u >> 16) & 1u)) >> 16;   // RNE bf16
    float hf = __uint_as_float(hb << 16);
    float lo = f - hf;
    uint32_t ul = __float_as_uint(lo);
    uint32_t lb = (ul + 0x7fffu + ((ul >> 16) & 1u)) >> 16;
    float lf = __uint_as_float(lb << 16);
    short hs = (short)hb, ls = (short)lb;
    size_t rb = (size_t)p * K3;
    A[rb + t] = hs;  A[rb + 128 + t] = hs;  A[rb + 256 + t] = ls;
    B[rb + t] = hs;  B[rb + 128 + t] = ls;  B[rb + 256 + t] = hs;
    float fh = hf + lf;
    red[t] = fh * fh;
    __syncthreads();
#pragma unroll
    for (int o = 64; o > 0; o >>= 1) {
        if (t < o) red[t] += red[t + o];
        __syncthreads();
    }
    if (t == 0) sq[p] = red[0];
}

// scan macro: per-thread row scan of one 64-row epilogue phase
#define SCAN_PHASE(PH, LD, LI, SQR)                                        \
    do {                                                                   \
        const int r_   = tid & 63;                                         \
        const int seg_ = tid >> 6;                                         \
        const int gr_  = row0 + (PH)*64 + r_;                              \
        const float* ep_ = &epi[r_ * EPI_STRIDE + seg_ * 32];              \
        _Pragma("unroll")                                                  \
        for (int cc = 0; cc < 32; ++cc) {                                  \
            float d2_ = (SQR) + ep_[cc];                                   \
            int gc_ = tc0 + seg_ * 32 + cc;                                \
            d2_ = (gr_ == gc_) ? 1e-30f : fmaxf(d2_, 1e-30f);              \
            insert6(d2_, gc_, LD, LI);                                     \
        }                                                                  \
    } while (0)

// K1: bf16-split MFMA distance + fused top-6 + fused zero-fill of out.
__global__ __launch_bounds__(256) void knn_mfma(const short* __restrict__ A,
                                                const short* __restrict__ B,
                                                const float* __restrict__ sq,
                                                float* __restrict__ part,
                                                float* __restrict__ out) {
    __shared__ __align__(16) short sA[BM * BK];     // 16 KB, swizzled 16B chunks
    __shared__ __align__(16) short sB[BN * BK];     // 16 KB
    __shared__ float epi[64 * EPI_STRIDE];          // 33.3 KB

    const int tid  = threadIdx.x;
    const int lane = tid & 63;
    const int w    = tid >> 6;       // wave 0..3
    const int wy   = w >> 1;
    const int wx   = w & 1;
    const int q    = lane >> 4;      // quad 0..3
    const int pl   = lane & 15;

    const int bx   = blockIdx.x;
    const int rb   = bx & 63;        // 64 row blocks
    const int cs   = bx >> 6;        // 8 splits
    const int row0 = rb * BM;
    const int col0 = cs * CPB2;

    // staging chunk decode (per-thread constants): phys chunk = w*256 + i*64 + lane
    int pS[4], cS[4];
#pragma unroll
    for (int i = 0; i < 4; ++i) {
        int ch = w * 256 + i * 64 + lane;
        pS[i] = ch >> 3;
        cS[i] = (ch & 7) ^ (pS[i] & 7);   // logical chunk at this phys slot
    }

    // frag LDS offsets (halfs), fixed across tiles/kk: phys = p*8 + (c ^ (p&7))
    int aOff[4][2], bOff[4][2];
#pragma unroll
    for (int fi = 0; fi < 4; ++fi) {
#pragma unroll
        for (int s = 0; s < 2; ++s) {
            int pa = wy * 64 + fi * 16 + pl;
            int ca = (s * 4 + q) ^ (pa & 7);
            aOff[fi][s] = (pa * 8 + ca) * 8;
            int pb = wx * 64 + fi * 16 + pl;
            int cb = (s * 4 + q) ^ (pb & 7);
            bOff[fi][s] = (pb * 8 + cb) * 8;
        }
    }

    const float sqr0 = sq[row0 + (tid & 63)];
    const float sqr1 = sq[row0 + 64 + (tid & 63)];

    float l0d[6], l1d[6];
    int   l0i[6], l1i[6];
#pragma unroll
    for (int i = 0; i < 6; ++i) {
        l0d[i] = 3.0e38f; l1d[i] = 3.0e38f; l0i[i] = 0; l1i[i] = 0;
    }

    for (int tile = 0; tile < NT2; ++tile) {
        const int tc0 = col0 + tile * BN;

        f32x4 acc[4][4];
#pragma unroll
        for (int fi = 0; fi < 4; ++fi)
#pragma unroll
            for (int fj = 0; fj < 4; ++fj) acc[fi][fj] = 0.0f;

        for (int kk = 0; kk < KITERS; ++kk) {
            __syncthreads();  // prior frag reads / epi scans complete
#pragma unroll
            for (int i = 0; i < 4; ++i) {
                const short* gA = A + (size_t)(row0 + pS[i]) * K3 + kk * 64 + cS[i] * 8;
                async16(gA, (char*)sA + (size_t)(w * 256 + i * 64) * 16);
                const short* gB = B + (size_t)(tc0 + pS[i]) * K3 + kk * 64 + cS[i] * 8;
                async16(gB, (char*)sB + (size_t)(w * 256 + i * 64) * 16);
            }
            __syncthreads();  // vmcnt drained before barrier => LDS valid
#pragma unroll
            for (int s = 0; s < 2; ++s) {
                bf16x8 af[4], bfr[4];
#pragma unroll
                for (int fi = 0; fi < 4; ++fi) af[fi]  = *(const bf16x8*)&sA[aOff[fi][s]];
#pragma unroll
                for (int fj = 0; fj < 4; ++fj) bfr[fj] = *(const bf16x8*)&sB[bOff[fj][s]];
#pragma unroll
                for (int fi = 0; fi < 4; ++fi)
#pragma unroll
                    for (int fj = 0; fj < 4; ++fj)
                        acc[fi][fj] = __builtin_amdgcn_mfma_f32_16x16x32_bf16(
                            af[fi], bfr[fj], acc[fi][fj], 0, 0, 0);
            }
        }

        // epilogue: write (sqc - 2*dot) per 64-row phase, scan per-row for top-6
        float sqc_r[4];
#pragma unroll
        for (int fj = 0; fj < 4; ++fj) sqc_r[fj] = sq[tc0 + wx * 64 + fj * 16 + pl];

        if (wy == 0) {
#pragma unroll
            for (int fi = 0; fi < 4; ++fi)
#pragma unroll
                for (int fj = 0; fj < 4; ++fj) {
                    const int colL = wx * 64 + fj * 16 + pl;
                    const float sc = sqc_r[fj];
#pragma unroll
                    for (int reg = 0; reg < 4; ++reg) {
                        const int r = fi * 16 + q * 4 + reg;
                        epi[r * EPI_STRIDE + colL] = sc - 2.0f * acc[fi][fj][reg];
                    }
                }
        }
        __syncthreads();
        SCAN_PHASE(0, l0d, l0i, sqr0);
        __syncthreads();
        if (wy == 1) {
#pragma unroll
            for (int fi = 0; fi < 4; ++fi)
#pragma unroll
                for (int fj = 0; fj < 4; ++fj) {
                    const int colL = wx * 64 + fj * 16 + pl;
                    const float sc = sqc_r[fj];
#pragma unroll
                    for (int reg = 0; reg < 4; ++reg) {
                        const int r = fi * 16 + q * 4 + reg;
                        epi[r * EPI_STRIDE + colL] = sc - 2.0f * acc[fi][fj][reg];
                    }
                }
        }
        __syncthreads();
        SCAN_PHASE(1, l1d, l1i, sqr1);

        // fused zero-fill of this tile's 128x128 output region (coalesced)
        {
            const int rr0 = tid >> 5;          // 0..7
            const int c4  = (tid & 31) * 4;
            const float4 z = make_float4(0.f, 0.f, 0.f, 0.f);
#pragma unroll
            for (int it = 0; it < 16; ++it)
                *(float4*)&out[(size_t)(row0 + it * 8 + rr0) * NPTS + tc0 + c4] = z;
        }
    }

    // block merge: 4 col-segment lists per row -> one partial per row per split
    __syncthreads();   // scans done before epi reused as merge scratch
    {
        const int r = tid & 63, seg = tid >> 6;
        float* d0 = &epi[(size_t)((r)      * 4 + seg) * 12];
        float* d1 = &epi[(size_t)((64 + r) * 4 + seg) * 12];
#pragma unroll
        for (int q2 = 0; q2 < 6; ++q2) {
            d0[q2] = l0d[q2]; d0[6 + q2] = __int_as_float(l0i[q2]);
            d1[q2] = l1d[q2]; d1[6 + q2] = __int_as_float(l1i[q2]);
        }
    }
    __syncthreads();
    if (tid < 128) {
        float md[6]; int mi[6];
#pragma unroll
        for (int q2 = 0; q2 < 6; ++q2) { md[q2] = 3.0e38f; mi[q2] = 0; }
#pragma unroll
        for (int g = 0; g < 4; ++g) {
            const float* src = &epi[(size_t)(tid * 4 + g) * 12];
#pragma unroll
            for (int q2 = 0; q2 < 6; ++q2)
                insert6(src[q2], __float_as_int(src[6 + q2]), md, mi);
        }
        float* dst = part + (size_t)(row0 + tid) * 96 + cs * 12;
#pragma unroll
        for (int q2 = 0; q2 < 6; ++q2) {
            dst[q2]     = md[q2];
            dst[6 + q2] = __int_as_float(mi[q2]);
        }
    }
}

// K2: merge 8 partial lists per row, compute weights, scatter 6 values.
__global__ __launch_bounds__(256) void knn_final(const float* __restrict__ part,
                                                 float* __restrict__ out) {
    const int r = blockIdx.x * 256 + threadIdx.x;
    float md[6]; int mi[6];
#pragma unroll
    for (int q = 0; q < 6; ++q) { md[q] = 3.0e38f; mi[q] = 0; }
    const float* p = part + (size_t)r * 96;
#pragma unroll
    for (int s = 0; s < 8; ++s)
#pragma unroll
        for (int q = 0; q < 6; ++q)
            insert6(p[s * 12 + q], __float_as_int(p[s * 12 + 6 + q]), md, mi);
    const float T = sqrtf(md[5]);
    float wv[6], norm = 0.f;
#pragma unroll
    for (int q = 0; q < 6; ++q) { wv[q] = T - sqrtf(md[q]) + 1e-10f; norm += wv[q]; }
    const float inv = 1.0f / fmaxf(norm, 1e-12f);
    const size_t base = (size_t)r * NPTS;
#pragma unroll
    for (int q = 0; q < 6; ++q) out[base + mi[q]] = wv[q] * inv;
}

// ------------------------- fallback fp32 path (round 1, passing) -------------------------
#define RB      32
#define CT      64
#define SPLITS  8
#define CPB     (NPTS / SPLITS)
#define NTILES  (CPB / CT)
#define PADS    132

__global__ __launch_bounds__(256) void knn_partial(const float* __restrict__ F,
                                                   float* __restrict__ out) {
    __shared__ float rowF[RB * PADS];
    __shared__ float colF[CT * PADS];
    __shared__ float sqr[RB];
    __shared__ float sqc[CT];

    const int tid  = threadIdx.x;
    const int bx   = blockIdx.x;
    const int rb   = bx & ((NPTS / RB) - 1);
    const int cs   = bx >> 8;
    const int row0 = rb * RB;
    const int col0 = cs * CPB;

#pragma unroll
    for (int m = 0; m < 4; ++m) {
        int flat = m * 256 + tid;
        int r = flat >> 5, kq = flat & 31;
        float4 v = *(const float4*)&F[(size_t)(row0 + r) * DIM + kq * 4];
        *(float4*)&rowF[r * PADS + kq * 4] = v;
    }
    __syncthreads();
    if (tid < RB) {
        float s = 0.f;
#pragma unroll
        for (int kq = 0; kq < 32; ++kq) {
            float4 v = *(const float4*)&rowF[tid * PADS + kq * 4];
            s += v.x * v.x + v.y * v.y + v.z * v.z + v.w * v.w;
        }
        sqr[tid] = s;
    }

    const int rl = tid >> 4;
    const int cl = tid & 15;

    float bd[2][6];
    int   bi[2][6];
#pragma unroll
    for (int i = 0; i < 2; ++i)
#pragma unroll
        for (int q = 0; q < 6; ++q) { bd[i][q] = 3.0e38f; bi[i][q] = 0; }

    for (int t = 0; t < NTILES; ++t) {
        const int cbase = col0 + t * CT;
        __syncthreads();
#pragma unroll
        for (int m = 0; m < 8; ++m) {
            int flat = m * 256 + tid;
            int c = flat >> 5, kq = flat & 31;
            float4 v = *(const float4*)&F[(size_t)(cbase + c) * DIM + kq * 4];
            *(float4*)&colF[c * PADS + kq * 4] = v;
        }
        __syncthreads();
        if (tid < CT) {
            float s = 0.f;
#pragma unroll
            for (int kq = 0; kq < 32; ++kq) {
                float4 v = *(const float4*)&colF[tid * PADS + kq * 4];
                s += v.x * v.x + v.y * v.y + v.z * v.z + v.w * v.w;
            }
            sqc[tid] = s;
        }
        __syncthreads();

        float acc[2][4];
#pragma unroll
        for (int i = 0; i < 2; ++i)
#pragma unroll
            for (int j = 0; j < 4; ++j) acc[i][j] = 0.f;

#pragma unroll 4
        for (int kq = 0; kq < 32; ++kq) {
            float4 a[2], b[4];
#pragma unroll
            for (int i = 0; i < 2; ++i)
                a[i] = *(const float4*)&rowF[(rl + 16 * i) * PADS + kq * 4];
#pragma unroll
            for (int j = 0; j < 4; ++j)
                b[j] = *(const float4*)&colF[(cl + 16 * j) * PADS + kq * 4];
#pragma unroll
            for (int i = 0; i < 2; ++i)
#pragma unroll
                for (int j = 0; j < 4; ++j) {
                    acc[i][j] = fmaf(a[i].x, b[j].x, acc[i][j]);
                    acc[i][j] = fmaf(a[i].y, b[j].y, acc[i][j]);
                    acc[i][j] = fmaf(a[i].z, b[j].z, acc[i][j]);
                    acc[i][j] = fmaf(a[i].w, b[j].w, acc[i][j]);
                }
        }

#pragma unroll
        for (int i = 0; i < 2; ++i) {
            const int r = rl + 16 * i;
            const int gr = row0 + r;
#pragma unroll
            for (int j = 0; j < 4; ++j) {
                const int c = cl + 16 * j;
                const int gc = cbase + c;
                float d2 = sqr[r] + sqc[c] - 2.0f * acc[i][j];
                d2 = (gr == gc) ? 1e-30f : fmaxf(d2, 1e-30f);
                insert6(d2, gc, bd[i], bi[i]);
            }
        }
    }

    __syncthreads();
    float* cd = colF;
    float* ci = rowF;
#pragma unroll
    for (int i = 0; i < 2; ++i) {
        const int r = rl + 16 * i;
#pragma unroll
        for (int q = 0; q < 6; ++q) {
            cd[(r * 16 + cl) * 6 + q] = bd[i][q];
            ci[(r * 16 + cl) * 6 + q] = __int_as_float(bi[i][q]);
        }
    }
    __syncthreads();
    if (tid < RB) {
        float md[6]; int mi[6];
#pragma unroll
        for (int q = 0; q < 6; ++q) { md[q] = 3.0e38f; mi[q] = 0; }
        for (int g = 0; g < 16; ++g) {
#pragma unroll
            for (int q = 0; q < 6; ++q)
                insert6(cd[(tid * 16 + g) * 6 + q],
                        __float_as_int(ci[(tid * 16 + g) * 6 + q]), md, mi);
        }
        float* dst = &out[(size_t)(row0 + tid) * NPTS + cs * 12];
#pragma unroll
        for (int q = 0; q < 6; ++q) {
            dst[q] = md[q];
            dst[6 + q] = __int_as_float(mi[q]);
        }
    }
}

__global__ __launch_bounds__(256) void knn_finalize(float* __restrict__ out) {
    __shared__ float pbuf[SPLITS * 12];
    __shared__ float w_s[6];
    __shared__ int   wi_s[6];

    const int    tid  = threadIdx.x;
    const size_t base = (size_t)blockIdx.x * NPTS;

    if (tid < SPLITS * 12) pbuf[tid] = out[base + tid];
    __syncthreads();

    if (tid == 0) {
        float md[6]; int mi[6];
#pragma unroll
        for (int q = 0; q < 6; ++q) { md[q] = 3.0e38f; mi[q] = 0; }
        for (int s = 0; s < SPLITS; ++s)
#pragma unroll
            for (int q = 0; q < 6; ++q)
                insert6(pbuf[s * 12 + q], __float_as_int(pbuf[s * 12 + 6 + q]), md, mi);
        const float T = sqrtf(md[5]);
        float w[6]; float norm = 0.f;
#pragma unroll
        for (int q = 0; q < 6; ++q) { w[q] = T - sqrtf(md[q]) + 1e-10f; norm += w[q]; }
        const float inv = 1.0f / fmaxf(norm, 1e-12f);
#pragma unroll
        for (int q = 0; q < 6; ++q) { w_s[q] = w[q] * inv; wi_s[q] = mi[q]; }
    }
    __syncthreads();

#pragma unroll
    for (int m = 0; m < 8; ++m)
        *(float4*)&out[base + (size_t)(m * 256 + tid) * 4] = make_float4(0.f, 0.f, 0.f, 0.f);
    __syncthreads();

    if (tid < 6) out[base + wi_s[tid]] = w_s[tid];
}

extern "C" void kernel_launch(void* const* d_in, const int* in_sizes, int n_in,
                              void* d_out, int out_size, void* d_ws, size_t ws_size,
                              hipStream_t stream) {
    const float* F   = (const float*)d_in[0];
    float*       out = (float*)d_out;
    if (ws_size >= WS_NEED) {
        short* Ap   = (short*)((char*)d_ws + WS_A);
        short* Bp   = (short*)((char*)d_ws + WS_B);
        float* sqp  = (float*)((char*)d_ws + WS_SQ);
        float* prt  = (float*)((char*)d_ws + WS_PART);
        prep<<<dim3(NPTS), dim3(128), 0, stream>>>(F, Ap, Bp, sqp);
        knn_mfma<<<dim3(64 * NSPLIT), dim3(256), 0, stream>>>(Ap, Bp, sqp, prt, out);
        knn_final<<<dim3(NPTS / 256), dim3(256), 0, stream>>>(prt, out);
    } else {
        knn_partial<<<dim3((NPTS / RB) * SPLITS), dim3(256), 0, stream>>>(F, out);
        knn_finalize<<<dim3(NPTS), dim3(256), 0, stream>>>(out);
    }
}

// Round 3
// 464.144 us; speedup vs baseline: 1.5231x; 1.2009x over previous
//
#include <hip/hip_runtime.h>
#include <cstddef>
#include <cstdint>

#define NPTS 8192
#define DIM  128

// MFMA path: 128x128 tiles, K3=384 split-bf16 ([hi|hi|lo].[hi|lo|hi]),
// BK=64 per staged step, double-buffered LDS, 1 barrier per step.
#define K3      384
#define BK      64
#define KITERS  (K3 / BK)        // 6
#define BM      128
#define BN      128
#define NSPLIT  8
#define CPB2    (NPTS / NSPLIT)  // 1024
#define NT2     (CPB2 / BN)      // 8

using bf16x8 = __attribute__((ext_vector_type(8))) short;
using f32x4  = __attribute__((ext_vector_type(4))) float;

// ws layout (bytes): Hi | Lo | sq | part
#define WS_HI   ((size_t)0)
#define WS_LO   ((size_t)NPTS * DIM * 2)            // 2 MB
#define WS_SQ   ((size_t)2 * NPTS * DIM * 2)        // 4 MB
#define WS_PART (WS_SQ + (size_t)NPTS * 4)          // +32 KB
#define WS_NEED (WS_PART + (size_t)NPTS * 96 * 4)   // ~7.3 MB

__device__ __forceinline__ void insert6(float d, int idx, float bd[6], int bi[6]) {
    if (d < bd[5]) {
        bd[5] = d; bi[5] = idx;
#pragma unroll
        for (int q = 5; q >= 1; --q) {
            if (bd[q] < bd[q - 1]) {
                float td = bd[q]; bd[q] = bd[q - 1]; bd[q - 1] = td;
                int   ti = bi[q]; bi[q] = bi[q - 1]; bi[q - 1] = ti;
            }
        }
    }
}

__device__ __forceinline__ void async16(const void* g, void* l) {
    __builtin_amdgcn_global_load_lds(
        (const __attribute__((address_space(1))) void*)g,
        (__attribute__((address_space(3))) void*)l,
        16, 0, 0);
}

// K0: elementwise fp32 -> (hi, lo) bf16 planes + per-row |f|^2 via shfl reduce.
__global__ __launch_bounds__(256) void prep2(const float* __restrict__ F,
                                             short* __restrict__ Hi,
                                             short* __restrict__ Lo,
                                             float* __restrict__ sq) {
    __shared__ float wsum[4];
    const int tid = threadIdx.x;
    const int idx = blockIdx.x * 256 + tid;
    float f = F[idx];
    uint32_t u  = __float_as_uint(f);
    uint32_t hb = (u + 0x7fffu + ((u >> 16) & 1u)) >> 16;     // RNE to bf16
    float hf = __uint_as_float(hb << 16);
    float lo = f - hf;
    uint32_t ul = __float_as_uint(lo);
    uint32_t lb = (ul + 0x7fffu + ((ul >> 16) & 1u)) >> 16;
    float lf = __uint_as_float(lb << 16);
    Hi[idx] = (short)hb;
    Lo[idx] = (short)lb;
    float fh = hf + lf;          // the value the GEMM actually sees
    float s  = fh * fh;
#pragma unroll
    for (int m = 32; m >= 1; m >>= 1) s += __shfl_xor(s, m, 64);
    if ((tid & 63) == 0) wsum[tid >> 6] = s;
    __syncthreads();
    if (tid < 2) sq[blockIdx.x * 2 + tid] = wsum[tid * 2] + wsum[tid * 2 + 1];
}

// K1: swapped-operand MFMA distance + in-register top-6 + fused zero-fill.
__global__ __launch_bounds__(256) void knn_mfma2(const short* __restrict__ Hi,
                                                 const short* __restrict__ Lo,
                                                 const float* __restrict__ sq,
                                                 float* __restrict__ part,
                                                 float* __restrict__ out) {
    // [buf 0|1] x (A-region 16 KB rows | B-region 16 KB cols); dump reuses 48 KB.
    __shared__ __align__(16) char smraw[65536];

    const int tid  = threadIdx.x;
    const int lane = tid & 63;
    const int w    = tid >> 6;        // wave 0..3
    const int wy   = w >> 1;          // col half
    const int wx   = w & 1;           // row half
    const int q    = lane >> 4;       // quad 0..3
    const int pl   = lane & 15;

    const int bx   = blockIdx.x;
    const int rb   = bx & 63;
    const int cs   = bx >> 6;
    const int row0 = rb * BM;
    const int col0 = cs * CPB2;

    // staging decode: slot = w*256 + i*64 + lane -> (point, logical chunk)
    int pS[4], cS[4];
#pragma unroll
    for (int i = 0; i < 4; ++i) {
        int ch = w * 256 + i * 64 + lane;
        pS[i] = ch >> 3;
        cS[i] = (ch & 7) ^ (pS[i] & 7);
    }

    // frag LDS byte offsets (fixed): phys chunk = point*8 + (kchunk ^ (point&7))
    int colOff[4][2], rowOff[4][2];
#pragma unroll
    for (int f = 0; f < 4; ++f) {
#pragma unroll
        for (int s = 0; s < 2; ++s) {
            int pc = wy * 64 + f * 16 + pl;             // col point (B region)
            int cc = (s * 4 + q) ^ (pc & 7);
            colOff[f][s] = (pc * 64 + cc * 8) * 2;
            int pr = wx * 64 + f * 16 + pl;             // row point (A region)
            int cr = (s * 4 + q) ^ (pr & 7);
            rowOff[f][s] = (pr * 64 + cr * 8) * 2;
        }
    }

    float sqr4[4];
#pragma unroll
    for (int fj = 0; fj < 4; ++fj) sqr4[fj] = sq[row0 + wx * 64 + fj * 16 + pl];

    float ld[4][6];
    int   li[4][6];
#pragma unroll
    for (int fj = 0; fj < 4; ++fj)
#pragma unroll
        for (int k = 0; k < 6; ++k) { ld[fj][k] = 3.0e38f; li[fj][k] = 0; }

    // stage step (nt,nk) into buffer b
    auto stage = [&](int b, int nt, int nk) {
        const short* plA = (nk >= 4) ? Lo : Hi;                 // sections hi,hi,lo
        const short* plB = ((nk >> 1) == 1) ? Lo : Hi;          // sections hi,lo,hi
        const int half = (nk & 1) * 64;
        const int tcn  = col0 + nt * BN;
        char* baseA = smraw + b * 32768;
        char* baseB = baseA + 16384;
#pragma unroll
        for (int i = 0; i < 4; ++i) {
            const short* gA = plA + (size_t)(row0 + pS[i]) * DIM + half + cS[i] * 8;
            async16(gA, baseA + (w * 256 + i * 64) * 16);
            const short* gB = plB + (size_t)(tcn + pS[i]) * DIM + half + cS[i] * 8;
            async16(gB, baseB + (w * 256 + i * 64) * 16);
        }
    };

    stage(0, 0, 0);
    int sidx = 0;

    for (int tile = 0; tile < NT2; ++tile) {
        const int tc0 = col0 + tile * BN;

        f32x4 acc[4][4];
#pragma unroll
        for (int fi = 0; fi < 4; ++fi)
#pragma unroll
            for (int fj = 0; fj < 4; ++fj) acc[fi][fj] = 0.0f;

        for (int kk = 0; kk < KITERS; ++kk) {
            const int b = sidx & 1;
            __syncthreads();   // drains in-flight stage (issued one step ago)
            int nk = kk + 1, nt = tile;
            if (nk == KITERS) { nk = 0; nt = tile + 1; }
            if (nt < NT2) stage(b ^ 1, nt, nk);

            char* baseA = smraw + b * 32768;
            char* baseB = baseA + 16384;
#pragma unroll
            for (int s = 0; s < 2; ++s) {
                bf16x8 cf[4], rf[4];
#pragma unroll
                for (int fi = 0; fi < 4; ++fi)
                    cf[fi] = *(const bf16x8*)(baseB + colOff[fi][s]);
#pragma unroll
                for (int fj = 0; fj < 4; ++fj)
                    rf[fj] = *(const bf16x8*)(baseA + rowOff[fj][s]);
#pragma unroll
                for (int fi = 0; fi < 4; ++fi)
#pragma unroll
                    for (int fj = 0; fj < 4; ++fj)
                        acc[fi][fj] = __builtin_amdgcn_mfma_f32_16x16x32_bf16(
                            cf[fi], rf[fj], acc[fi][fj], 0, 0, 0);
            }
            ++sidx;
        }

        // in-register epilogue: D[m=col][n=row]; this thread owns
        // rows r = wx*64+fj*16+pl, cols c = wy*64+fi*16+q*4+reg.
        const bool diag = (tc0 == row0);
        float4 sqc4[4];
#pragma unroll
        for (int fi = 0; fi < 4; ++fi)
            sqc4[fi] = *(const float4*)&sq[tc0 + wy * 64 + fi * 16 + q * 4];

#pragma unroll
        for (int fj = 0; fj < 4; ++fj) {
            const float sr = sqr4[fj];
            const int   r  = wx * 64 + fj * 16 + pl;
#pragma unroll
            for (int fi = 0; fi < 4; ++fi) {
                const float* sc = (const float*)&sqc4[fi];
#pragma unroll
                for (int reg = 0; reg < 4; ++reg) {
                    float d2 = fmaf(-2.0f, acc[fi][fj][reg], sr + sc[reg]);
                    d2 = fmaxf(d2, 1e-30f);
                    const int c = wy * 64 + fi * 16 + q * 4 + reg;
                    if (diag && r == c) d2 = 1e-30f;    // self-distance
                    insert6(d2, tc0 + c, ld[fj], li[fj]);
                }
            }
        }

        // fused zero-fill of this 128x128 output region (coalesced float4)
        {
            const int rr0 = tid >> 5;
            const int c4  = (tid & 31) * 4;
            const float4 z = make_float4(0.f, 0.f, 0.f, 0.f);
#pragma unroll
            for (int it = 0; it < 16; ++it)
                *(float4*)&out[(size_t)(row0 + it * 8 + rr0) * NPTS + tc0 + c4] = z;
        }
    }

    // merge: 8 lists per row (2 wy-waves x 4 q) -> one partial per row.
    __syncthreads();                       // all frag reads done; reuse smraw
    float* dump = (float*)smraw;           // 128 rows * 8 copies * 12 = 48 KB
#pragma unroll
    for (int fj = 0; fj < 4; ++fj) {
        const int r    = wx * 64 + fj * 16 + pl;
        const int copy = wy * 4 + q;
        float* d = &dump[(size_t)(r * 8 + copy) * 12];
#pragma unroll
        for (int k = 0; k < 6; ++k) {
            d[k]     = ld[fj][k];
            d[6 + k] = __int_as_float(li[fj][k]);
        }
    }
    __syncthreads();
    if (tid < 128) {
        float md[6]; int mi[6];
#pragma unroll
        for (int k = 0; k < 6; ++k) { md[k] = 3.0e38f; mi[k] = 0; }
        const float* src = &dump[(size_t)tid * 96];
#pragma unroll
        for (int g = 0; g < 8; ++g)
#pragma unroll
            for (int k = 0; k < 6; ++k)
                insert6(src[g * 12 + k], __float_as_int(src[g * 12 + 6 + k]), md, mi);
        float* dst = part + (size_t)(row0 + tid) * 96 + cs * 12;
#pragma unroll
        for (int k = 0; k < 6; ++k) {
            dst[k]     = md[k];
            dst[6 + k] = __int_as_float(mi[k]);
        }
    }
}

// K2: merge 8 split-partials per row, compute weights, scatter 6 values.
__global__ __launch_bounds__(64) void final2(const float* __restrict__ part,
                                             float* __restrict__ out) {
    const int r = blockIdx.x * 64 + threadIdx.x;
    float md[6]; int mi[6];
#pragma unroll
    for (int k = 0; k < 6; ++k) { md[k] = 3.0e38f; mi[k] = 0; }
    const float* p = part + (size_t)r * 96;
#pragma unroll
    for (int s = 0; s < 8; ++s)
#pragma unroll
        for (int k = 0; k < 6; ++k)
            insert6(p[s * 12 + k], __float_as_int(p[s * 12 + 6 + k]), md, mi);
    const float T = sqrtf(md[5]);
    float wv[6], norm = 0.f;
#pragma unroll
    for (int k = 0; k < 6; ++k) { wv[k] = T - sqrtf(md[k]) + 1e-10f; norm += wv[k]; }
    const float inv = 1.0f / fmaxf(norm, 1e-12f);
    const size_t base = (size_t)r * NPTS;
#pragma unroll
    for (int k = 0; k < 6; ++k) out[base + mi[k]] = wv[k] * inv;
}

// ------------------- fallback fp32 path (round 1, passing) -------------------
#define RB      32
#define CT      64
#define SPLITS  8
#define CPB     (NPTS / SPLITS)
#define NTILES  (CPB / CT)
#define PADS    132

__global__ __launch_bounds__(256) void knn_partial(const float* __restrict__ F,
                                                   float* __restrict__ out) {
    __shared__ float rowF[RB * PADS];
    __shared__ float colF[CT * PADS];
    __shared__ float sqr[RB];
    __shared__ float sqc[CT];

    const int tid  = threadIdx.x;
    const int bx   = blockIdx.x;
    const int rb   = bx & ((NPTS / RB) - 1);
    const int cs   = bx >> 8;
    const int row0 = rb * RB;
    const int col0 = cs * CPB;

#pragma unroll
    for (int m = 0; m < 4; ++m) {
        int flat = m * 256 + tid;
        int r = flat >> 5, kq = flat & 31;
        float4 v = *(const float4*)&F[(size_t)(row0 + r) * DIM + kq * 4];
        *(float4*)&rowF[r * PADS + kq * 4] = v;
    }
    __syncthreads();
    if (tid < RB) {
        float s = 0.f;
#pragma unroll
        for (int kq = 0; kq < 32; ++kq) {
            float4 v = *(const float4*)&rowF[tid * PADS + kq * 4];
            s += v.x * v.x + v.y * v.y + v.z * v.z + v.w * v.w;
        }
        sqr[tid] = s;
    }

    const int rl = tid >> 4;
    const int cl = tid & 15;

    float bd[2][6];
    int   bi[2][6];
#pragma unroll
    for (int i = 0; i < 2; ++i)
#pragma unroll
        for (int k = 0; k < 6; ++k) { bd[i][k] = 3.0e38f; bi[i][k] = 0; }

    for (int t = 0; t < NTILES; ++t) {
        const int cbase = col0 + t * CT;
        __syncthreads();
#pragma unroll
        for (int m = 0; m < 8; ++m) {
            int flat = m * 256 + tid;
            int c = flat >> 5, kq = flat & 31;
            float4 v = *(const float4*)&F[(size_t)(cbase + c) * DIM + kq * 4];
            *(float4*)&colF[c * PADS + kq * 4] = v;
        }
        __syncthreads();
        if (tid < CT) {
            float s = 0.f;
#pragma unroll
            for (int kq = 0; kq < 32; ++kq) {
                float4 v = *(const float4*)&colF[tid * PADS + kq * 4];
                s += v.x * v.x + v.y * v.y + v.z * v.z + v.w * v.w;
            }
            sqc[tid] = s;
        }
        __syncthreads();

        float acc[2][4];
#pragma unroll
        for (int i = 0; i < 2; ++i)
#pragma unroll
            for (int j = 0; j < 4; ++j) acc[i][j] = 0.f;

#pragma unroll 4
        for (int kq = 0; kq < 32; ++kq) {
            float4 a[2], b[4];
#pragma unroll
            for (int i = 0; i < 2; ++i)
                a[i] = *(const float4*)&rowF[(rl + 16 * i) * PADS + kq * 4];
#pragma unroll
            for (int j = 0; j < 4; ++j)
                b[j] = *(const float4*)&colF[(cl + 16 * j) * PADS + kq * 4];
#pragma unroll
            for (int i = 0; i < 2; ++i)
#pragma unroll
                for (int j = 0; j < 4; ++j) {
                    acc[i][j] = fmaf(a[i].x, b[j].x, acc[i][j]);
                    acc[i][j] = fmaf(a[i].y, b[j].y, acc[i][j]);
                    acc[i][j] = fmaf(a[i].z, b[j].z, acc[i][j]);
                    acc[i][j] = fmaf(a[i].w, b[j].w, acc[i][j]);
                }
        }

#pragma unroll
        for (int i = 0; i < 2; ++i) {
            const int r = rl + 16 * i;
            const int gr = row0 + r;
#pragma unroll
            for (int j = 0; j < 4; ++j) {
                const int c = cl + 16 * j;
                const int gc = cbase + c;
                float d2 = sqr[r] + sqc[c] - 2.0f * acc[i][j];
                d2 = (gr == gc) ? 1e-30f : fmaxf(d2, 1e-30f);
                insert6(d2, gc, bd[i], bi[i]);
            }
        }
    }

    __syncthreads();
    float* cd = colF;
    float* ci = rowF;
#pragma unroll
    for (int i = 0; i < 2; ++i) {
        const int r = rl + 16 * i;
#pragma unroll
        for (int k = 0; k < 6; ++k) {
            cd[(r * 16 + cl) * 6 + k] = bd[i][k];
            ci[(r * 16 + cl) * 6 + k] = __int_as_float(bi[i][k]);
        }
    }
    __syncthreads();
    if (tid < RB) {
        float md[6]; int mi[6];
#pragma unroll
        for (int k = 0; k < 6; ++k) { md[k] = 3.0e38f; mi[k] = 0; }
        for (int g = 0; g < 16; ++g) {
#pragma unroll
            for (int k = 0; k < 6; ++k)
                insert6(cd[(tid * 16 + g) * 6 + k],
                        __float_as_int(ci[(tid * 16 + g) * 6 + k]), md, mi);
        }
        float* dst = &out[(size_t)(row0 + tid) * NPTS + cs * 12];
#pragma unroll
        for (int k = 0; k < 6; ++k) {
            dst[k] = md[k];
            dst[6 + k] = __int_as_float(mi[k]);
        }
    }
}

__global__ __launch_bounds__(256) void knn_finalize(float* __restrict__ out) {
    __shared__ float pbuf[SPLITS * 12];
    __shared__ float w_s[6];
    __shared__ int   wi_s[6];

    const int    tid  = threadIdx.x;
    const size_t base = (size_t)blockIdx.x * NPTS;

    if (tid < SPLITS * 12) pbuf[tid] = out[base + tid];
    __syncthreads();

    if (tid == 0) {
        float md[6]; int mi[6];
#pragma unroll
        for (int k = 0; k < 6; ++k) { md[k] = 3.0e38f; mi[k] = 0; }
        for (int s = 0; s < SPLITS; ++s)
#pragma unroll
            for (int k = 0; k < 6; ++k)
                insert6(pbuf[s * 12 + k], __float_as_int(pbuf[s * 12 + 6 + k]), md, mi);
        const float T = sqrtf(md[5]);
        float w[6]; float norm = 0.f;
#pragma unroll
        for (int k = 0; k < 6; ++k) { w[k] = T - sqrtf(md[k]) + 1e-10f; norm += w[k]; }
        const float inv = 1.0f / fmaxf(norm, 1e-12f);
#pragma unroll
        for (int k = 0; k < 6; ++k) { w_s[k] = w[k] * inv; wi_s[k] = mi[k]; }
    }
    __syncthreads();

#pragma unroll
    for (int m = 0; m < 8; ++m)
        *(float4*)&out[base + (size_t)(m * 256 + tid) * 4] = make_float4(0.f, 0.f, 0.f, 0.f);
    __syncthreads();

    if (tid < 6) out[base + wi_s[tid]] = w_s[tid];
}

extern "C" void kernel_launch(void* const* d_in, const int* in_sizes, int n_in,
                              void* d_out, int out_size, void* d_ws, size_t ws_size,
                              hipStream_t stream) {
    const float* F   = (const float*)d_in[0];
    float*       out = (float*)d_out;
    if (ws_size >= WS_NEED) {
        short* Hi  = (short*)((char*)d_ws + WS_HI);
        short* Lo  = (short*)((char*)d_ws + WS_LO);
        float* sqp = (float*)((char*)d_ws + WS_SQ);
        float* prt = (float*)((char*)d_ws + WS_PART);
        prep2<<<dim3(NPTS * DIM / 256), dim3(256), 0, stream>>>(F, Hi, Lo, sqp);
        knn_mfma2<<<dim3(64 * NSPLIT), dim3(256), 0, stream>>>(Hi, Lo, sqp, prt, out);
        final2<<<dim3(NPTS / 64), dim3(64), 0, stream>>>(prt, out);
    } else {
        knn_partial<<<dim3((NPTS / RB) * SPLITS), dim3(256), 0, stream>>>(F, out);
        knn_finalize<<<dim3(NPTS), dim3(256), 0, stream>>>(out);
    }
}

// Round 6
// 370.901 us; speedup vs baseline: 1.9060x; 1.2514x over previous
//
#include <hip/hip_runtime.h>
#include <cstddef>
#include <cstdint>

#define NPTS 8192
#define DIM  128

// MFMA path: 128x128 tiles, K3=384 split-bf16 ([hi|hi|lo].[hi|lo|hi]),
// BK=64 per staged step, double-buffered LDS, 1 barrier per step,
// packed-key top-6, tail zero-fill (no barrier after stores).
#define K3      384
#define BK      64
#define KITERS  (K3 / BK)        // 6
#define BM      128
#define BN      128
#define NSPLIT  8
#define CPB2    (NPTS / NSPLIT)  // 1024
#define NT2     (CPB2 / BN)      // 8

using bf16x8 = __attribute__((ext_vector_type(8))) short;
using f32x4  = __attribute__((ext_vector_type(4))) float;

// ws layout (bytes): Hi | Lo | sq | part (8192 rows x 8 splits x 6 packed keys)
#define WS_HI   ((size_t)0)
#define WS_LO   ((size_t)NPTS * DIM * 2)            // 2 MB
#define WS_SQ   ((size_t)2 * NPTS * DIM * 2)        // 4 MB
#define WS_PART (WS_SQ + (size_t)NPTS * 4)          // +32 KB
#define WS_NEED (WS_PART + (size_t)NPTS * 48 * 4)   // ~5.7 MB

// branchless sorted-ascending insert of packed key (positive floats only)
__device__ __forceinline__ void ins6(float t, float bd[6]) {
#pragma unroll
    for (int q = 0; q < 6; ++q) {
        float lo = fminf(bd[q], t);
        t        = fmaxf(bd[q], t);
        bd[q]    = lo;
    }
}

// classic (d2, idx) insert for the small final merge
__device__ __forceinline__ void insert6(float d, int idx, float bd[6], int bi[6]) {
    if (d < bd[5]) {
        bd[5] = d; bi[5] = idx;
#pragma unroll
        for (int q = 5; q >= 1; --q) {
            if (bd[q] < bd[q - 1]) {
                float td = bd[q]; bd[q] = bd[q - 1]; bd[q - 1] = td;
                int   ti = bi[q]; bi[q] = bi[q - 1]; bi[q - 1] = ti;
            }
        }
    }
}

__device__ __forceinline__ void async16(const void* g, void* l) {
    __builtin_amdgcn_global_load_lds(
        (const __attribute__((address_space(1))) void*)g,
        (__attribute__((address_space(3))) void*)l,
        16, 0, 0);
}

// K0: elementwise fp32 -> (hi, lo) bf16 planes + per-row |f|^2 via shfl reduce.
__global__ __launch_bounds__(256) void prep2(const float* __restrict__ F,
                                             short* __restrict__ Hi,
                                             short* __restrict__ Lo,
                                             float* __restrict__ sq) {
    __shared__ float wsum[4];
    const int tid = threadIdx.x;
    const int idx = blockIdx.x * 256 + tid;
    float f = F[idx];
    uint32_t u  = __float_as_uint(f);
    uint32_t hb = (u + 0x7fffu + ((u >> 16) & 1u)) >> 16;     // RNE to bf16
    float hf = __uint_as_float(hb << 16);
    float lo = f - hf;
    uint32_t ul = __float_as_uint(lo);
    uint32_t lb = (ul + 0x7fffu + ((ul >> 16) & 1u)) >> 16;
    float lf = __uint_as_float(lb << 16);
    Hi[idx] = (short)hb;
    Lo[idx] = (short)lb;
    float fh = hf + lf;          // the value the GEMM actually sees
    float s  = fh * fh;
#pragma unroll
    for (int m = 32; m >= 1; m >>= 1) s += __shfl_xor(s, m, 64);
    if ((tid & 63) == 0) wsum[tid >> 6] = s;
    __syncthreads();
    if (tid < 2) sq[blockIdx.x * 2 + tid] = wsum[tid * 2] + wsum[tid * 2 + 1];
}

// K1: swapped-operand MFMA distance + packed-key top-6 + tail zero-fill.
__global__ __launch_bounds__(256, 2) void knn_mfma3(const short* __restrict__ Hi,
                                                    const short* __restrict__ Lo,
                                                    const float* __restrict__ sq,
                                                    float* __restrict__ part,
                                                    float* __restrict__ out) {
    __shared__ __align__(16) char smraw[65536];   // 2 x (16KB A | 16KB B); dump reuses 24KB

    const int tid  = threadIdx.x;
    const int lane = tid & 63;
    const int w    = tid >> 6;        // wave 0..3
    const int wy   = w >> 1;          // col half
    const int wx   = w & 1;           // row half
    const int q    = lane >> 4;       // quad 0..3
    const int pl   = lane & 15;

    const int bx   = blockIdx.x;
    const int rb   = bx & 63;
    const int cs   = bx >> 6;
    const int row0 = rb * BM;
    const int col0 = cs * CPB2;

    // staging decode: slot = w*256 + i*64 + lane -> (point, logical chunk)
    int pS[4], cS[4];
#pragma unroll
    for (int i = 0; i < 4; ++i) {
        int ch = w * 256 + i * 64 + lane;
        pS[i] = ch >> 3;
        cS[i] = (ch & 7) ^ (pS[i] & 7);
    }

    // frag LDS byte offsets: phys chunk = point*8 + (kchunk ^ (point&7))
    int colOff[4][2], rowOff[4][2];
#pragma unroll
    for (int f = 0; f < 4; ++f) {
#pragma unroll
        for (int s = 0; s < 2; ++s) {
            int pc = wy * 64 + f * 16 + pl;
            int cc = (s * 4 + q) ^ (pc & 7);
            colOff[f][s] = (pc * 64 + cc * 8) * 2;
            int pr = wx * 64 + f * 16 + pl;
            int cr = (s * 4 + q) ^ (pr & 7);
            rowOff[f][s] = (pr * 64 + cr * 8) * 2;
        }
    }

    float sqr4[4];
#pragma unroll
    for (int fj = 0; fj < 4; ++fj) sqr4[fj] = sq[row0 + wx * 64 + fj * 16 + pl];

    // packed-key top-6 per owned row (4 rows per thread)
    float bd[4][6];
#pragma unroll
    for (int fj = 0; fj < 4; ++fj)
#pragma unroll
        for (int k = 0; k < 6; ++k) bd[fj][k] = 3.0e38f;

    auto stage = [&](int b, int nt, int nk) {
        const short* plA = (nk >= 4) ? Lo : Hi;                 // A sections hi,hi,lo
        const short* plB = ((nk >> 1) == 1) ? Lo : Hi;          // B sections hi,lo,hi
        const int half = (nk & 1) * 64;
        const int tcn  = col0 + nt * BN;
        char* baseA = smraw + b * 32768;
        char* baseB = baseA + 16384;
#pragma unroll
        for (int i = 0; i < 4; ++i) {
            const short* gA = plA + (size_t)(row0 + pS[i]) * DIM + half + cS[i] * 8;
            async16(gA, baseA + (w * 256 + i * 64) * 16);
            const short* gB = plB + (size_t)(tcn + pS[i]) * DIM + half + cS[i] * 8;
            async16(gB, baseB + (w * 256 + i * 64) * 16);
        }
    };

    stage(0, 0, 0);
    int sidx = 0;

    for (int tile = 0; tile < NT2; ++tile) {
        const int tc0 = col0 + tile * BN;

        f32x4 acc[4][4];
#pragma unroll
        for (int fi = 0; fi < 4; ++fi)
#pragma unroll
            for (int fj = 0; fj < 4; ++fj) acc[fi][fj] = 0.0f;

        for (int kk = 0; kk < KITERS; ++kk) {
            const int b = sidx & 1;
            __syncthreads();
            int nk = kk + 1, nt = tile;
            if (nk == KITERS) { nk = 0; nt = tile + 1; }
            if (nt < NT2) stage(b ^ 1, nt, nk);

            char* baseA = smraw + b * 32768;
            char* baseB = baseA + 16384;
#pragma unroll
            for (int s = 0; s < 2; ++s) {
                bf16x8 cf[4], rf[4];
#pragma unroll
                for (int fi = 0; fi < 4; ++fi)
                    cf[fi] = *(const bf16x8*)(baseB + colOff[fi][s]);
#pragma unroll
                for (int fj = 0; fj < 4; ++fj)
                    rf[fj] = *(const bf16x8*)(baseA + rowOff[fj][s]);
#pragma unroll
                for (int fi = 0; fi < 4; ++fi)
#pragma unroll
                    for (int fj = 0; fj < 4; ++fj)
                        acc[fi][fj] = __builtin_amdgcn_mfma_f32_16x16x32_bf16(
                            cf[fi], rf[fj], acc[fi][fj], 0, 0, 0);
            }
            ++sidx;
        }

        // in-register epilogue: rows r = wx*64+fj*16+pl, cols c = wy*64+fi*16+q*4+reg
        const bool diag = (tc0 == row0);
        float4 sqc4[4];
#pragma unroll
        for (int fi = 0; fi < 4; ++fi)
            sqc4[fi] = *(const float4*)&sq[tc0 + wy * 64 + fi * 16 + q * 4];

#pragma unroll
        for (int fj = 0; fj < 4; ++fj) {
            const float sr = sqr4[fj];
            const int   r  = wx * 64 + fj * 16 + pl;
#pragma unroll
            for (int fi = 0; fi < 4; ++fi) {
                const float* sc = (const float*)&sqc4[fi];
#pragma unroll
                for (int reg = 0; reg < 4; ++reg) {
                    const int c = wy * 64 + fi * 16 + q * 4 + reg;
                    float d2 = fmaf(-2.0f, acc[fi][fj][reg], sr + sc[reg]);
                    d2 = fmaxf(d2, 1e-30f);
                    if (diag && r == c) d2 = 1e-30f;    // self-distance
                    uint32_t kb = (__float_as_uint(d2) & 0xFFFFFC00u)
                                  | (uint32_t)(tile * BN + c);   // 10-bit local col
                    ins6(__uint_as_float(kb), bd[fj]);
                }
            }
        }
    }

    // block merge: 8 lists per row (wy x q) -> 6 packed keys per row per split
    __syncthreads();                       // all frag reads done; reuse smraw
    float* dump = (float*)smraw;           // 128 rows * 8 copies * 6 = 24 KB
#pragma unroll
    for (int fj = 0; fj < 4; ++fj) {
        const int r    = wx * 64 + fj * 16 + pl;
        const int copy = wy * 4 + q;
        float* d = &dump[(size_t)(r * 8 + copy) * 6];
#pragma unroll
        for (int k = 0; k < 6; ++k) d[k] = bd[fj][k];
    }
    __syncthreads();
    if (tid < 128) {
        float md[6];
#pragma unroll
        for (int k = 0; k < 6; ++k) md[k] = 3.0e38f;
        const float* src = &dump[(size_t)tid * 48];
#pragma unroll
        for (int g = 0; g < 48; ++g) ins6(src[g], md);
        float* dst = part + (size_t)(row0 + tid) * 48 + cs * 6;
#pragma unroll
        for (int k = 0; k < 6; ++k) dst[k] = md[k];
    }

    // tail zero-fill: 128 rows x 1024 cols = 32768 float4 (256 float4 per row),
    // fire-and-forget, no barrier after.
    {
        const float4 z = make_float4(0.f, 0.f, 0.f, 0.f);
#pragma unroll 8
        for (int it = 0; it < 128; ++it) {
            int flat = it * 256 + tid;
            int r    = flat >> 8;           // 0..127   (256 float4 per row)
            int c4   = (flat & 255) * 4;    // 0..1020
            *(float4*)&out[(size_t)(row0 + r) * NPTS + col0 + c4] = z;
        }
    }
}

// K2: merge 8 packed-key lists per row (direct global reads, no LDS),
// compute weights, scatter 6 values.
__global__ __launch_bounds__(256) void final3(const float* __restrict__ part,
                                              float* __restrict__ out) {
    const int r = blockIdx.x * 256 + threadIdx.x;
    const float4* p4 = (const float4*)(part + (size_t)r * 48);
    float4 buf[12];
#pragma unroll
    for (int i = 0; i < 12; ++i) buf[i] = p4[i];
    const float* keys = (const float*)buf;

    float md[6]; int mi[6];
#pragma unroll
    for (int k = 0; k < 6; ++k) { md[k] = 3.0e38f; mi[k] = 0; }
#pragma unroll
    for (int s = 0; s < 8; ++s)
#pragma unroll
        for (int k = 0; k < 6; ++k) {
            uint32_t kb = __float_as_uint(keys[s * 6 + k]);
            float d2 = __uint_as_float(kb & 0xFFFFFC00u);
            int  col = s * CPB2 + (int)(kb & 1023u);
            insert6(d2, col, md, mi);
        }
    const float T = sqrtf(md[5]);
    float wv[6], norm = 0.f;
#pragma unroll
    for (int k = 0; k < 6; ++k) { wv[k] = T - sqrtf(md[k]) + 1e-10f; norm += wv[k]; }
    const float inv = 1.0f / fmaxf(norm, 1e-12f);
    const size_t base = (size_t)r * NPTS;
#pragma unroll
    for (int k = 0; k < 6; ++k) out[base + mi[k]] = wv[k] * inv;
}

// ------------------- fallback fp32 path (round 1, passing) -------------------
#define RB      32
#define CT      64
#define SPLITS  8
#define CPB     (NPTS / SPLITS)
#define NTILES  (CPB / CT)
#define PADS    132

__global__ __launch_bounds__(256) void knn_partial(const float* __restrict__ F,
                                                   float* __restrict__ out) {
    __shared__ float rowF[RB * PADS];
    __shared__ float colF[CT * PADS];
    __shared__ float sqr[RB];
    __shared__ float sqc[CT];

    const int tid  = threadIdx.x;
    const int bx   = blockIdx.x;
    const int rb   = bx & ((NPTS / RB) - 1);
    const int cs   = bx >> 8;
    const int row0 = rb * RB;
    const int col0 = cs * CPB;

#pragma unroll
    for (int m = 0; m < 4; ++m) {
        int flat = m * 256 + tid;
        int r = flat >> 5, kq = flat & 31;
        float4 v = *(const float4*)&F[(size_t)(row0 + r) * DIM + kq * 4];
        *(float4*)&rowF[r * PADS + kq * 4] = v;
    }
    __syncthreads();
    if (tid < RB) {
        float s = 0.f;
#pragma unroll
        for (int kq = 0; kq < 32; ++kq) {
            float4 v = *(const float4*)&rowF[tid * PADS + kq * 4];
            s += v.x * v.x + v.y * v.y + v.z * v.z + v.w * v.w;
        }
        sqr[tid] = s;
    }

    const int rl = tid >> 4;
    const int cl = tid & 15;

    float bd[2][6];
    int   bi[2][6];
#pragma unroll
    for (int i = 0; i < 2; ++i)
#pragma unroll
        for (int k = 0; k < 6; ++k) { bd[i][k] = 3.0e38f; bi[i][k] = 0; }

    for (int t = 0; t < NTILES; ++t) {
        const int cbase = col0 + t * CT;
        __syncthreads();
#pragma unroll
        for (int m = 0; m < 8; ++m) {
            int flat = m * 256 + tid;
            int c = flat >> 5, kq = flat & 31;
            float4 v = *(const float4*)&F[(size_t)(cbase + c) * DIM + kq * 4];
            *(float4*)&colF[c * PADS + kq * 4] = v;
        }
        __syncthreads();
        if (tid < CT) {
            float s = 0.f;
#pragma unroll
            for (int kq = 0; kq < 32; ++kq) {
                float4 v = *(const float4*)&colF[tid * PADS + kq * 4];
                s += v.x * v.x + v.y * v.y + v.z * v.z + v.w * v.w;
            }
            sqc[tid] = s;
        }
        __syncthreads();

        float acc[2][4];
#pragma unroll
        for (int i = 0; i < 2; ++i)
#pragma unroll
            for (int j = 0; j < 4; ++j) acc[i][j] = 0.f;

#pragma unroll 4
        for (int kq = 0; kq < 32; ++kq) {
            float4 a[2], b[4];
#pragma unroll
            for (int i = 0; i < 2; ++i)
                a[i] = *(const float4*)&rowF[(rl + 16 * i) * PADS + kq * 4];
#pragma unroll
            for (int j = 0; j < 4; ++j)
                b[j] = *(const float4*)&colF[(cl + 16 * j) * PADS + kq * 4];
#pragma unroll
            for (int i = 0; i < 2; ++i)
#pragma unroll
                for (int j = 0; j < 4; ++j) {
                    acc[i][j] = fmaf(a[i].x, b[j].x, acc[i][j]);
                    acc[i][j] = fmaf(a[i].y, b[j].y, acc[i][j]);
                    acc[i][j] = fmaf(a[i].z, b[j].z, acc[i][j]);
                    acc[i][j] = fmaf(a[i].w, b[j].w, acc[i][j]);
                }
        }

#pragma unroll
        for (int i = 0; i < 2; ++i) {
            const int r = rl + 16 * i;
            const int gr = row0 + r;
#pragma unroll
            for (int j = 0; j < 4; ++j) {
                const int c = cl + 16 * j;
                const int gc = cbase + c;
                float d2 = sqr[r] + sqc[c] - 2.0f * acc[i][j];
                d2 = (gr == gc) ? 1e-30f : fmaxf(d2, 1e-30f);
                insert6(d2, gc, bd[i], bi[i]);
            }
        }
    }

    __syncthreads();
    float* cd = colF;
    float* ci = rowF;
#pragma unroll
    for (int i = 0; i < 2; ++i) {
        const int r = rl + 16 * i;
#pragma unroll
        for (int k = 0; k < 6; ++k) {
            cd[(r * 16 + cl) * 6 + k] = bd[i][k];
            ci[(r * 16 + cl) * 6 + k] = __int_as_float(bi[i][k]);
        }
    }
    __syncthreads();
    if (tid < RB) {
        float md[6]; int mi[6];
#pragma unroll
        for (int k = 0; k < 6; ++k) { md[k] = 3.0e38f; mi[k] = 0; }
        for (int g = 0; g < 16; ++g) {
#pragma unroll
            for (int k = 0; k < 6; ++k)
                insert6(cd[(tid * 16 + g) * 6 + k],
                        __float_as_int(ci[(tid * 16 + g) * 6 + k]), md, mi);
        }
        float* dst = &out[(size_t)(row0 + tid) * NPTS + cs * 12];
#pragma unroll
        for (int k = 0; k < 6; ++k) {
            dst[k] = md[k];
            dst[6 + k] = __int_as_float(mi[k]);
        }
    }
}

__global__ __launch_bounds__(256) void knn_finalize(float* __restrict__ out) {
    __shared__ float pbuf[SPLITS * 12];
    __shared__ float w_s[6];
    __shared__ int   wi_s[6];

    const int    tid  = threadIdx.x;
    const size_t base = (size_t)blockIdx.x * NPTS;

    if (tid < SPLITS * 12) pbuf[tid] = out[base + tid];
    __syncthreads();

    if (tid == 0) {
        float md[6]; int mi[6];
#pragma unroll
        for (int k = 0; k < 6; ++k) { md[k] = 3.0e38f; mi[k] = 0; }
        for (int s = 0; s < SPLITS; ++s)
#pragma unroll
            for (int k = 0; k < 6; ++k)
                insert6(pbuf[s * 12 + k], __float_as_int(pbuf[s * 12 + 6 + k]), md, mi);
        const float T = sqrtf(md[5]);
        float w[6]; float norm = 0.f;
#pragma unroll
        for (int k = 0; k < 6; ++k) { w[k] = T - sqrtf(md[k]) + 1e-10f; norm += w[k]; }
        const float inv = 1.0f / fmaxf(norm, 1e-12f);
#pragma unroll
        for (int k = 0; k < 6; ++k) { w_s[k] = w[k] * inv; wi_s[k] = mi[k]; }
    }
    __syncthreads();

#pragma unroll
    for (int m = 0; m < 8; ++m)
        *(float4*)&out[base + (size_t)(m * 256 + tid) * 4] = make_float4(0.f, 0.f, 0.f, 0.f);
    __syncthreads();

    if (tid < 6) out[base + wi_s[tid]] = w_s[tid];
}

extern "C" void kernel_launch(void* const* d_in, const int* in_sizes, int n_in,
                              void* d_out, int out_size, void* d_ws, size_t ws_size,
                              hipStream_t stream) {
    const float* F   = (const float*)d_in[0];
    float*       out = (float*)d_out;
    if (ws_size >= WS_NEED) {
        short* Hi  = (short*)((char*)d_ws + WS_HI);
        short* Lo  = (short*)((char*)d_ws + WS_LO);
        float* sqp = (float*)((char*)d_ws + WS_SQ);
        float* prt = (float*)((char*)d_ws + WS_PART);
        prep2<<<dim3(NPTS * DIM / 256), dim3(256), 0, stream>>>(F, Hi, Lo, sqp);
        knn_mfma3<<<dim3(64 * NSPLIT), dim3(256), 0, stream>>>(Hi, Lo, sqp, prt, out);
        final3<<<dim3(NPTS / 256), dim3(256), 0, stream>>>(prt, out);
    } else {
        knn_partial<<<dim3((NPTS / RB) * SPLITS), dim3(256), 0, stream>>>(F, out);
        knn_finalize<<<dim3(NPTS), dim3(256), 0, stream>>>(out);
    }
}

// Round 8
// 333.027 us; speedup vs baseline: 2.1228x; 1.1137x over previous
//
#include <hip/hip_runtime.h>
#include <cstddef>
#include <cstdint>

#define NPTS 8192
#define DIM  128

// MFMA path: 128x128 tiles, K3=384 split-bf16 ([hi|hi|lo].[hi|lo|hi]),
// BK=64 per staged step, double-buffered LDS, 1 barrier per step,
// packed-key top-6, zero-fill interleaved into the K-loop (3 f32x4/thread/step,
// issued right after the barrier; nontemporal).
#define K3      384
#define BK      64
#define KITERS  (K3 / BK)        // 6
#define BM      128
#define BN      128
#define NSPLIT  8
#define CPB2    (NPTS / NSPLIT)  // 1024
#define NT2     (CPB2 / BN)      // 8

using bf16x8 = __attribute__((ext_vector_type(8))) short;
using f32x4  = __attribute__((ext_vector_type(4))) float;

// ws layout (bytes): Hi | Lo | sq | part (8192 rows x 8 splits x 6 packed keys)
#define WS_HI   ((size_t)0)
#define WS_LO   ((size_t)NPTS * DIM * 2)            // 2 MB
#define WS_SQ   ((size_t)2 * NPTS * DIM * 2)        // 4 MB
#define WS_PART (WS_SQ + (size_t)NPTS * 4)          // +32 KB
#define WS_NEED (WS_PART + (size_t)NPTS * 48 * 4)   // ~5.7 MB

// branchless sorted-ascending insert of packed key (positive floats only)
__device__ __forceinline__ void ins6(float t, float bd[6]) {
#pragma unroll
    for (int q = 0; q < 6; ++q) {
        float lo = fminf(bd[q], t);
        t        = fmaxf(bd[q], t);
        bd[q]    = lo;
    }
}

// classic (d2, idx) insert for the small final merge
__device__ __forceinline__ void insert6(float d, int idx, float bd[6], int bi[6]) {
    if (d < bd[5]) {
        bd[5] = d; bi[5] = idx;
#pragma unroll
        for (int q = 5; q >= 1; --q) {
            if (bd[q] < bd[q - 1]) {
                float td = bd[q]; bd[q] = bd[q - 1]; bd[q - 1] = td;
                int   ti = bi[q]; bi[q] = bi[q - 1]; bi[q - 1] = ti;
            }
        }
    }
}

__device__ __forceinline__ void async16(const void* g, void* l) {
    __builtin_amdgcn_global_load_lds(
        (const __attribute__((address_space(1))) void*)g,
        (__attribute__((address_space(3))) void*)l,
        16, 0, 0);
}

// K0: elementwise fp32 -> (hi, lo) bf16 planes + per-row |f|^2 via shfl reduce.
__global__ __launch_bounds__(256) void prep2(const float* __restrict__ F,
                                             short* __restrict__ Hi,
                                             short* __restrict__ Lo,
                                             float* __restrict__ sq) {
    __shared__ float wsum[4];
    const int tid = threadIdx.x;
    const int idx = blockIdx.x * 256 + tid;
    float f = F[idx];
    uint32_t u  = __float_as_uint(f);
    uint32_t hb = (u + 0x7fffu + ((u >> 16) & 1u)) >> 16;     // RNE to bf16
    float hf = __uint_as_float(hb << 16);
    float lo = f - hf;
    uint32_t ul = __float_as_uint(lo);
    uint32_t lb = (ul + 0x7fffu + ((ul >> 16) & 1u)) >> 16;
    float lf = __uint_as_float(lb << 16);
    Hi[idx] = (short)hb;
    Lo[idx] = (short)lb;
    float fh = hf + lf;          // the value the GEMM actually sees
    float s  = fh * fh;
#pragma unroll
    for (int m = 32; m >= 1; m >>= 1) s += __shfl_xor(s, m, 64);
    if ((tid & 63) == 0) wsum[tid >> 6] = s;
    __syncthreads();
    if (tid < 2) sq[blockIdx.x * 2 + tid] = wsum[tid * 2] + wsum[tid * 2 + 1];
}

// K1: swapped-operand MFMA distance + packed-key top-6 + interleaved zero-fill.
__global__ __launch_bounds__(256, 2) void knn_mfma3(const short* __restrict__ Hi,
                                                    const short* __restrict__ Lo,
                                                    const float* __restrict__ sq,
                                                    float* __restrict__ part,
                                                    float* __restrict__ out) {
    __shared__ __align__(16) char smraw[65536];   // 2 x (16KB A | 16KB B); dump reuses 24KB

    const int tid  = threadIdx.x;
    const int lane = tid & 63;
    const int w    = tid >> 6;        // wave 0..3
    const int wy   = w >> 1;          // col half
    const int wx   = w & 1;           // row half
    const int q    = lane >> 4;       // quad 0..3
    const int pl   = lane & 15;

    const int bx   = blockIdx.x;
    const int rb   = bx & 63;
    const int cs   = bx >> 6;
    const int row0 = rb * BM;
    const int col0 = cs * CPB2;

    // staging decode: slot = w*256 + i*64 + lane -> (point, logical chunk)
    int pS[4], cS[4];
#pragma unroll
    for (int i = 0; i < 4; ++i) {
        int ch = w * 256 + i * 64 + lane;
        pS[i] = ch >> 3;
        cS[i] = (ch & 7) ^ (pS[i] & 7);
    }

    // frag LDS byte offsets: phys chunk = point*8 + (kchunk ^ (point&7))
    int colOff[4][2], rowOff[4][2];
#pragma unroll
    for (int f = 0; f < 4; ++f) {
#pragma unroll
        for (int s = 0; s < 2; ++s) {
            int pc = wy * 64 + f * 16 + pl;
            int cc = (s * 4 + q) ^ (pc & 7);
            colOff[f][s] = (pc * 64 + cc * 8) * 2;
            int pr = wx * 64 + f * 16 + pl;
            int cr = (s * 4 + q) ^ (pr & 7);
            rowOff[f][s] = (pr * 64 + cr * 8) * 2;
        }
    }

    float sqr4[4];
#pragma unroll
    for (int fj = 0; fj < 4; ++fj) sqr4[fj] = sq[row0 + wx * 64 + fj * 16 + pl];

    // packed-key top-6 per owned row (4 rows per thread)
    float bd[4][6];
#pragma unroll
    for (int fj = 0; fj < 4; ++fj)
#pragma unroll
        for (int k = 0; k < 6; ++k) bd[fj][k] = 3.0e38f;

    auto stage = [&](int b, int nt, int nk) {
        const short* plA = (nk >= 4) ? Lo : Hi;                 // A sections hi,hi,lo
        const short* plB = ((nk >> 1) == 1) ? Lo : Hi;          // B sections hi,lo,hi
        const int half = (nk & 1) * 64;
        const int tcn  = col0 + nt * BN;
        char* baseA = smraw + b * 32768;
        char* baseB = baseA + 16384;
#pragma unroll
        for (int i = 0; i < 4; ++i) {
            const short* gA = plA + (size_t)(row0 + pS[i]) * DIM + half + cS[i] * 8;
            async16(gA, baseA + (w * 256 + i * 64) * 16);
            const short* gB = plB + (size_t)(tcn + pS[i]) * DIM + half + cS[i] * 8;
            async16(gB, baseB + (w * 256 + i * 64) * 16);
        }
    };

    stage(0, 0, 0);
    int sidx = 0;

    const f32x4 z4 = {0.f, 0.f, 0.f, 0.f};

    for (int tile = 0; tile < NT2; ++tile) {
        const int tc0 = col0 + tile * BN;

        f32x4 acc[4][4];
#pragma unroll
        for (int fi = 0; fi < 4; ++fi)
#pragma unroll
            for (int fj = 0; fj < 4; ++fj) acc[fi][fj] = 0.0f;

        for (int kk = 0; kk < KITERS; ++kk) {
            const int b = sidx & 1;
            __syncthreads();
            int nk = kk + 1, nt = tile;
            if (nk == KITERS) { nk = 0; nt = tile + 1; }
            if (nt < NT2) stage(b ^ 1, nt, nk);

            // interleaved zero-fill quota: 3 f32x4/thread/step, guarded.
            // Issued right after the barrier so stores have a full step to
            // ack at L2 before the next barrier's vmcnt drain.
            {
                int base = sidx * 768 + tid;
#pragma unroll
                for (int it = 0; it < 3; ++it) {
                    int flat = base + it * 256;
                    if (flat < 32768) {
                        int r  = flat >> 8;           // 0..127
                        int c4 = (flat & 255) * 4;    // 0..1020
                        __builtin_nontemporal_store(
                            z4, (f32x4*)&out[(size_t)(row0 + r) * NPTS + col0 + c4]);
                    }
                }
            }

            char* baseA = smraw + b * 32768;
            char* baseB = baseA + 16384;
#pragma unroll
            for (int s = 0; s < 2; ++s) {
                bf16x8 cf[4], rf[4];
#pragma unroll
                for (int fi = 0; fi < 4; ++fi)
                    cf[fi] = *(const bf16x8*)(baseB + colOff[fi][s]);
#pragma unroll
                for (int fj = 0; fj < 4; ++fj)
                    rf[fj] = *(const bf16x8*)(baseA + rowOff[fj][s]);
#pragma unroll
                for (int fi = 0; fi < 4; ++fi)
#pragma unroll
                    for (int fj = 0; fj < 4; ++fj)
                        acc[fi][fj] = __builtin_amdgcn_mfma_f32_16x16x32_bf16(
                            cf[fi], rf[fj], acc[fi][fj], 0, 0, 0);
            }
            ++sidx;
        }

        // in-register epilogue: rows r = wx*64+fj*16+pl, cols c = wy*64+fi*16+q*4+reg
        const bool diag = (tc0 == row0);
        float4 sqc4[4];
#pragma unroll
        for (int fi = 0; fi < 4; ++fi)
            sqc4[fi] = *(const float4*)&sq[tc0 + wy * 64 + fi * 16 + q * 4];

#pragma unroll
        for (int fj = 0; fj < 4; ++fj) {
            const float sr = sqr4[fj];
            const int   r  = wx * 64 + fj * 16 + pl;
#pragma unroll
            for (int fi = 0; fi < 4; ++fi) {
                const float* sc = (const float*)&sqc4[fi];
#pragma unroll
                for (int reg = 0; reg < 4; ++reg) {
                    const int c = wy * 64 + fi * 16 + q * 4 + reg;
                    float d2 = fmaf(-2.0f, acc[fi][fj][reg], sr + sc[reg]);
                    d2 = fmaxf(d2, 1e-30f);
                    if (diag && r == c) d2 = 1e-30f;    // self-distance
                    uint32_t kb = (__float_as_uint(d2) & 0xFFFFFC00u)
                                  | (uint32_t)(tile * BN + c);   // 10-bit local col
                    ins6(__uint_as_float(kb), bd[fj]);
                }
            }
        }
    }

    // block merge: 8 lists per row (wy x q) -> 6 packed keys per row per split
    __syncthreads();                       // all frag reads done; reuse smraw
    float* dump = (float*)smraw;           // 128 rows * 8 copies * 6 = 24 KB
#pragma unroll
    for (int fj = 0; fj < 4; ++fj) {
        const int r    = wx * 64 + fj * 16 + pl;
        const int copy = wy * 4 + q;
        float* d = &dump[(size_t)(r * 8 + copy) * 6];
#pragma unroll
        for (int k = 0; k < 6; ++k) d[k] = bd[fj][k];
    }
    __syncthreads();
    if (tid < 128) {
        float md[6];
#pragma unroll
        for (int k = 0; k < 6; ++k) md[k] = 3.0e38f;
        const float* src = &dump[(size_t)tid * 48];
#pragma unroll
        for (int g = 0; g < 48; ++g) ins6(src[g], md);
        float* dst = part + (size_t)(row0 + tid) * 48 + cs * 6;
#pragma unroll
        for (int k = 0; k < 6; ++k) dst[k] = md[k];
    }
}

// K2: merge 8 packed-key lists per row (direct global reads, no LDS),
// compute weights, scatter 6 values.
__global__ __launch_bounds__(256) void final3(const float* __restrict__ part,
                                              float* __restrict__ out) {
    const int r = blockIdx.x * 256 + threadIdx.x;
    const float4* p4 = (const float4*)(part + (size_t)r * 48);
    float4 buf[12];
#pragma unroll
    for (int i = 0; i < 12; ++i) buf[i] = p4[i];
    const float* keys = (const float*)buf;

    float md[6]; int mi[6];
#pragma unroll
    for (int k = 0; k < 6; ++k) { md[k] = 3.0e38f; mi[k] = 0; }
#pragma unroll
    for (int s = 0; s < 8; ++s)
#pragma unroll
        for (int k = 0; k < 6; ++k) {
            uint32_t kb = __float_as_uint(keys[s * 6 + k]);
            float d2 = __uint_as_float(kb & 0xFFFFFC00u);
            int  col = s * CPB2 + (int)(kb & 1023u);
            insert6(d2, col, md, mi);
        }
    const float T = sqrtf(md[5]);
    float wv[6], norm = 0.f;
#pragma unroll
    for (int k = 0; k < 6; ++k) { wv[k] = T - sqrtf(md[k]) + 1e-10f; norm += wv[k]; }
    const float inv = 1.0f / fmaxf(norm, 1e-12f);
    const size_t base = (size_t)r * NPTS;
#pragma unroll
    for (int k = 0; k < 6; ++k) out[base + mi[k]] = wv[k] * inv;
}

// ------------------- fallback fp32 path (round 1, passing) -------------------
#define RB      32
#define CT      64
#define SPLITS  8
#define CPB     (NPTS / SPLITS)
#define NTILES  (CPB / CT)
#define PADS    132

__global__ __launch_bounds__(256) void knn_partial(const float* __restrict__ F,
                                                   float* __restrict__ out) {
    __shared__ float rowF[RB * PADS];
    __shared__ float colF[CT * PADS];
    __shared__ float sqr[RB];
    __shared__ float sqc[CT];

    const int tid  = threadIdx.x;
    const int bx   = blockIdx.x;
    const int rb   = bx & ((NPTS / RB) - 1);
    const int cs   = bx >> 8;
    const int row0 = rb * RB;
    const int col0 = cs * CPB;

#pragma unroll
    for (int m = 0; m < 4; ++m) {
        int flat = m * 256 + tid;
        int r = flat >> 5, kq = flat & 31;
        float4 v = *(const float4*)&F[(size_t)(row0 + r) * DIM + kq * 4];
        *(float4*)&rowF[r * PADS + kq * 4] = v;
    }
    __syncthreads();
    if (tid < RB) {
        float s = 0.f;
#pragma unroll
        for (int kq = 0; kq < 32; ++kq) {
            float4 v = *(const float4*)&rowF[tid * PADS + kq * 4];
            s += v.x * v.x + v.y * v.y + v.z * v.z + v.w * v.w;
        }
        sqr[tid] = s;
    }

    const int rl = tid >> 4;
    const int cl = tid & 15;

    float bd[2][6];
    int   bi[2][6];
#pragma unroll
    for (int i = 0; i < 2; ++i)
#pragma unroll
        for (int k = 0; k < 6; ++k) { bd[i][k] = 3.0e38f; bi[i][k] = 0; }

    for (int t = 0; t < NTILES; ++t) {
        const int cbase = col0 + t * CT;
        __syncthreads();
#pragma unroll
        for (int m = 0; m < 8; ++m) {
            int flat = m * 256 + tid;
            int c = flat >> 5, kq = flat & 31;
            float4 v = *(const float4*)&F[(size_t)(cbase + c) * DIM + kq * 4];
            *(float4*)&colF[c * PADS + kq * 4] = v;
        }
        __syncthreads();
        if (tid < CT) {
            float s = 0.f;
#pragma unroll
            for (int kq = 0; kq < 32; ++kq) {
                float4 v = *(const float4*)&colF[tid * PADS + kq * 4];
                s += v.x * v.x + v.y * v.y + v.z * v.z + v.w * v.w;
            }
            sqc[tid] = s;
        }
        __syncthreads();

        float acc[2][4];
#pragma unroll
        for (int i = 0; i < 2; ++i)
#pragma unroll
            for (int j = 0; j < 4; ++j) acc[i][j] = 0.f;

#pragma unroll 4
        for (int kq = 0; kq < 32; ++kq) {
            float4 a[2], b[4];
#pragma unroll
            for (int i = 0; i < 2; ++i)
                a[i] = *(const float4*)&rowF[(rl + 16 * i) * PADS + kq * 4];
#pragma unroll
            for (int j = 0; j < 4; ++j)
                b[j] = *(const float4*)&colF[(cl + 16 * j) * PADS + kq * 4];
#pragma unroll
            for (int i = 0; i < 2; ++i)
#pragma unroll
                for (int j = 0; j < 4; ++j) {
                    acc[i][j] = fmaf(a[i].x, b[j].x, acc[i][j]);
                    acc[i][j] = fmaf(a[i].y, b[j].y, acc[i][j]);
                    acc[i][j] = fmaf(a[i].z, b[j].z, acc[i][j]);
                    acc[i][j] = fmaf(a[i].w, b[j].w, acc[i][j]);
                }
        }

#pragma unroll
        for (int i = 0; i < 2; ++i) {
            const int r = rl + 16 * i;
            const int gr = row0 + r;
#pragma unroll
            for (int j = 0; j < 4; ++j) {
                const int c = cl + 16 * j;
                const int gc = cbase + c;
                float d2 = sqr[r] + sqc[c] - 2.0f * acc[i][j];
                d2 = (gr == gc) ? 1e-30f : fmaxf(d2, 1e-30f);
                insert6(d2, gc, bd[i], bi[i]);
            }
        }
    }

    __syncthreads();
    float* cd = colF;
    float* ci = rowF;
#pragma unroll
    for (int i = 0; i < 2; ++i) {
        const int r = rl + 16 * i;
#pragma unroll
        for (int k = 0; k < 6; ++k) {
            cd[(r * 16 + cl) * 6 + k] = bd[i][k];
            ci[(r * 16 + cl) * 6 + k] = __int_as_float(bi[i][k]);
        }
    }
    __syncthreads();
    if (tid < RB) {
        float md[6]; int mi[6];
#pragma unroll
        for (int k = 0; k < 6; ++k) { md[k] = 3.0e38f; mi[k] = 0; }
        for (int g = 0; g < 16; ++g) {
#pragma unroll
            for (int k = 0; k < 6; ++k)
                insert6(cd[(tid * 16 + g) * 6 + k],
                        __float_as_int(ci[(tid * 16 + g) * 6 + k]), md, mi);
        }
        float* dst = &out[(size_t)(row0 + tid) * NPTS + cs * 12];
#pragma unroll
        for (int k = 0; k < 6; ++k) {
            dst[k] = md[k];
            dst[6 + k] = __int_as_float(mi[k]);
        }
    }
}

__global__ __launch_bounds__(256) void knn_finalize(float* __restrict__ out) {
    __shared__ float pbuf[SPLITS * 12];
    __shared__ float w_s[6];
    __shared__ int   wi_s[6];

    const int    tid  = threadIdx.x;
    const size_t base = (size_t)blockIdx.x * NPTS;

    if (tid < SPLITS * 12) pbuf[tid] = out[base + tid];
    __syncthreads();

    if (tid == 0) {
        float md[6]; int mi[6];
#pragma unroll
        for (int k = 0; k < 6; ++k) { md[k] = 3.0e38f; mi[k] = 0; }
        for (int s = 0; s < SPLITS; ++s)
#pragma unroll
            for (int k = 0; k < 6; ++k)
                insert6(pbuf[s * 12 + k], __float_as_int(pbuf[s * 12 + 6 + k]), md, mi);
        const float T = sqrtf(md[5]);
        float w[6]; float norm = 0.f;
#pragma unroll
        for (int k = 0; k < 6; ++k) { w[k] = T - sqrtf(md[k]) + 1e-10f; norm += w[k]; }
        const float inv = 1.0f / fmaxf(norm, 1e-12f);
#pragma unroll
        for (int k = 0; k < 6; ++k) { w_s[k] = w[k] * inv; wi_s[k] = mi[k]; }
    }
    __syncthreads();

#pragma unroll
    for (int m = 0; m < 8; ++m)
        *(float4*)&out[base + (size_t)(m * 256 + tid) * 4] = make_float4(0.f, 0.f, 0.f, 0.f);
    __syncthreads();

    if (tid < 6) out[base + wi_s[tid]] = w_s[tid];
}

extern "C" void kernel_launch(void* const* d_in, const int* in_sizes, int n_in,
                              void* d_out, int out_size, void* d_ws, size_t ws_size,
                              hipStream_t stream) {
    const float* F   = (const float*)d_in[0];
    float*       out = (float*)d_out;
    if (ws_size >= WS_NEED) {
        short* Hi  = (short*)((char*)d_ws + WS_HI);
        short* Lo  = (short*)((char*)d_ws + WS_LO);
        float* sqp = (float*)((char*)d_ws + WS_SQ);
        float* prt = (float*)((char*)d_ws + WS_PART);
        prep2<<<dim3(NPTS * DIM / 256), dim3(256), 0, stream>>>(F, Hi, Lo, sqp);
        knn_mfma3<<<dim3(64 * NSPLIT), dim3(256), 0, stream>>>(Hi, Lo, sqp, prt, out);
        final3<<<dim3(NPTS / 256), dim3(256), 0, stream>>>(prt, out);
    } else {
        knn_partial<<<dim3((NPTS / RB) * SPLITS), dim3(256), 0, stream>>>(F, out);
        knn_finalize<<<dim3(NPTS), dim3(256), 0, stream>>>(out);
    }
}

// Round 9
// 311.519 us; speedup vs baseline: 2.2693x; 1.0690x over previous
//
#include <hip/hip_runtime.h>
#include <cstddef>
#include <cstdint>

#define NPTS 8192
#define DIM  128

// MFMA path: 128x128 tiles, K3=256 split-bf16 (A'=[hi|lo] . B'=[hi|hi], i.e.
// (hiA+loA).hiB — drops the hiA.loB term; error ~0.025 RMS on d^2, well under
// the 2e-2 weight gate). BK=64 per staged step, double-buffered LDS, 1 barrier
// per step, packed-key top-6, zero-fill interleaved (4 f32x4/thread/step).
#define K3      256
#define BK      64
#define KITERS  (K3 / BK)        // 4
#define BM      128
#define BN      128
#define NSPLIT  8
#define CPB2    (NPTS / NSPLIT)  // 1024
#define NT2     (CPB2 / BN)      // 8

using bf16x8 = __attribute__((ext_vector_type(8))) short;
using f32x4  = __attribute__((ext_vector_type(4))) float;

// ws layout (bytes): Hi | Lo | sq | part (8192 rows x 8 splits x 6 packed keys)
#define WS_HI   ((size_t)0)
#define WS_LO   ((size_t)NPTS * DIM * 2)            // 2 MB
#define WS_SQ   ((size_t)2 * NPTS * DIM * 2)        // 4 MB
#define WS_PART (WS_SQ + (size_t)NPTS * 4)          // +32 KB
#define WS_NEED (WS_PART + (size_t)NPTS * 48 * 4)   // ~5.7 MB

// branchless sorted-ascending insert of packed key (positive floats only)
__device__ __forceinline__ void ins6(float t, float bd[6]) {
#pragma unroll
    for (int q = 0; q < 6; ++q) {
        float lo = fminf(bd[q], t);
        t        = fmaxf(bd[q], t);
        bd[q]    = lo;
    }
}

// classic (d2, idx) insert for the small final merge
__device__ __forceinline__ void insert6(float d, int idx, float bd[6], int bi[6]) {
    if (d < bd[5]) {
        bd[5] = d; bi[5] = idx;
#pragma unroll
        for (int q = 5; q >= 1; --q) {
            if (bd[q] < bd[q - 1]) {
                float td = bd[q]; bd[q] = bd[q - 1]; bd[q - 1] = td;
                int   ti = bi[q]; bi[q] = bi[q - 1]; bi[q - 1] = ti;
            }
        }
    }
}

__device__ __forceinline__ void async16(const void* g, void* l) {
    __builtin_amdgcn_global_load_lds(
        (const __attribute__((address_space(1))) void*)g,
        (__attribute__((address_space(3))) void*)l,
        16, 0, 0);
}

// K0: elementwise fp32 -> (hi, lo) bf16 planes + per-row |f|^2 via shfl reduce.
__global__ __launch_bounds__(256) void prep2(const float* __restrict__ F,
                                             short* __restrict__ Hi,
                                             short* __restrict__ Lo,
                                             float* __restrict__ sq) {
    __shared__ float wsum[4];
    const int tid = threadIdx.x;
    const int idx = blockIdx.x * 256 + tid;
    float f = F[idx];
    uint32_t u  = __float_as_uint(f);
    uint32_t hb = (u + 0x7fffu + ((u >> 16) & 1u)) >> 16;     // RNE to bf16
    float hf = __uint_as_float(hb << 16);
    float lo = f - hf;
    uint32_t ul = __float_as_uint(lo);
    uint32_t lb = (ul + 0x7fffu + ((ul >> 16) & 1u)) >> 16;
    float lf = __uint_as_float(lb << 16);
    Hi[idx] = (short)hb;
    Lo[idx] = (short)lb;
    float fh = hf + lf;          // the value the GEMM's A-side sees
    float s  = fh * fh;
#pragma unroll
    for (int m = 32; m >= 1; m >>= 1) s += __shfl_xor(s, m, 64);
    if ((tid & 63) == 0) wsum[tid >> 6] = s;
    __syncthreads();
    if (tid < 2) sq[blockIdx.x * 2 + tid] = wsum[tid * 2] + wsum[tid * 2 + 1];
}

// K1: swapped-operand MFMA distance + packed-key top-6 + interleaved zero-fill.
__global__ __launch_bounds__(256, 2) void knn_mfma3(const short* __restrict__ Hi,
                                                    const short* __restrict__ Lo,
                                                    const float* __restrict__ sq,
                                                    float* __restrict__ part,
                                                    float* __restrict__ out) {
    __shared__ __align__(16) char smraw[65536];   // 2 x (16KB A | 16KB B); dump reuses 24KB

    const int tid  = threadIdx.x;
    const int lane = tid & 63;
    const int w    = tid >> 6;        // wave 0..3
    const int wy   = w >> 1;          // col half
    const int wx   = w & 1;           // row half
    const int q    = lane >> 4;       // quad 0..3
    const int pl   = lane & 15;

    const int bx   = blockIdx.x;
    const int rb   = bx & 63;
    const int cs   = bx >> 6;
    const int row0 = rb * BM;
    const int col0 = cs * CPB2;

    // staging decode: slot = w*256 + i*64 + lane -> (point, logical chunk)
    int pS[4], cS[4];
#pragma unroll
    for (int i = 0; i < 4; ++i) {
        int ch = w * 256 + i * 64 + lane;
        pS[i] = ch >> 3;
        cS[i] = (ch & 7) ^ (pS[i] & 7);
    }

    // frag LDS byte offsets: phys chunk = point*8 + (kchunk ^ (point&7))
    int colOff[4][2], rowOff[4][2];
#pragma unroll
    for (int f = 0; f < 4; ++f) {
#pragma unroll
        for (int s = 0; s < 2; ++s) {
            int pc = wy * 64 + f * 16 + pl;
            int cc = (s * 4 + q) ^ (pc & 7);
            colOff[f][s] = (pc * 64 + cc * 8) * 2;
            int pr = wx * 64 + f * 16 + pl;
            int cr = (s * 4 + q) ^ (pr & 7);
            rowOff[f][s] = (pr * 64 + cr * 8) * 2;
        }
    }

    float sqr4[4];
#pragma unroll
    for (int fj = 0; fj < 4; ++fj) sqr4[fj] = sq[row0 + wx * 64 + fj * 16 + pl];

    // packed-key top-6 per owned row (4 rows per thread)
    float bd[4][6];
#pragma unroll
    for (int fj = 0; fj < 4; ++fj)
#pragma unroll
        for (int k = 0; k < 6; ++k) bd[fj][k] = 3.0e38f;

    auto stage = [&](int b, int nt, int nk) {
        const short* plA = (nk >= 2) ? Lo : Hi;     // A sections: hi, lo
        const short* plB = Hi;                      // B sections: hi, hi
        const int half = (nk & 1) * 64;
        const int tcn  = col0 + nt * BN;
        char* baseA = smraw + b * 32768;
        char* baseB = baseA + 16384;
#pragma unroll
        for (int i = 0; i < 4; ++i) {
            const short* gA = plA + (size_t)(row0 + pS[i]) * DIM + half + cS[i] * 8;
            async16(gA, baseA + (w * 256 + i * 64) * 16);
            const short* gB = plB + (size_t)(tcn + pS[i]) * DIM + half + cS[i] * 8;
            async16(gB, baseB + (w * 256 + i * 64) * 16);
        }
    };

    stage(0, 0, 0);
    int sidx = 0;

    const f32x4 z4 = {0.f, 0.f, 0.f, 0.f};

    for (int tile = 0; tile < NT2; ++tile) {
        const int tc0 = col0 + tile * BN;

        f32x4 acc[4][4];
#pragma unroll
        for (int fi = 0; fi < 4; ++fi)
#pragma unroll
            for (int fj = 0; fj < 4; ++fj) acc[fi][fj] = 0.0f;

        for (int kk = 0; kk < KITERS; ++kk) {
            const int b = sidx & 1;
            __syncthreads();
            int nk = kk + 1, nt = tile;
            if (nk == KITERS) { nk = 0; nt = tile + 1; }
            if (nt < NT2) stage(b ^ 1, nt, nk);

            // interleaved zero-fill quota: 4 f32x4/thread/step.
            // 32 steps x 1024 f32x4 = 32768 = the full 128x1024 region.
            {
                int base = sidx * 1024 + tid;
#pragma unroll
                for (int it = 0; it < 4; ++it) {
                    int flat = base + it * 256;
                    int r  = flat >> 8;           // 0..127
                    int c4 = (flat & 255) * 4;    // 0..1020
                    __builtin_nontemporal_store(
                        z4, (f32x4*)&out[(size_t)(row0 + r) * NPTS + col0 + c4]);
                }
            }

            char* baseA = smraw + b * 32768;
            char* baseB = baseA + 16384;
#pragma unroll
            for (int s = 0; s < 2; ++s) {
                bf16x8 cf[4], rf[4];
#pragma unroll
                for (int fi = 0; fi < 4; ++fi)
                    cf[fi] = *(const bf16x8*)(baseB + colOff[fi][s]);
#pragma unroll
                for (int fj = 0; fj < 4; ++fj)
                    rf[fj] = *(const bf16x8*)(baseA + rowOff[fj][s]);
#pragma unroll
                for (int fi = 0; fi < 4; ++fi)
#pragma unroll
                    for (int fj = 0; fj < 4; ++fj)
                        acc[fi][fj] = __builtin_amdgcn_mfma_f32_16x16x32_bf16(
                            cf[fi], rf[fj], acc[fi][fj], 0, 0, 0);
            }
            ++sidx;
        }

        // in-register epilogue: rows r = wx*64+fj*16+pl, cols c = wy*64+fi*16+q*4+reg
        const bool diag = (tc0 == row0);
        float4 sqc4[4];
#pragma unroll
        for (int fi = 0; fi < 4; ++fi)
            sqc4[fi] = *(const float4*)&sq[tc0 + wy * 64 + fi * 16 + q * 4];

#pragma unroll
        for (int fj = 0; fj < 4; ++fj) {
            const float sr = sqr4[fj];
            const int   r  = wx * 64 + fj * 16 + pl;
#pragma unroll
            for (int fi = 0; fi < 4; ++fi) {
                const float* sc = (const float*)&sqc4[fi];
#pragma unroll
                for (int reg = 0; reg < 4; ++reg) {
                    const int c = wy * 64 + fi * 16 + q * 4 + reg;
                    float d2 = fmaf(-2.0f, acc[fi][fj][reg], sr + sc[reg]);
                    d2 = fmaxf(d2, 1e-30f);
                    if (diag && r == c) d2 = 1e-30f;    // self-distance
                    uint32_t kb = (__float_as_uint(d2) & 0xFFFFFC00u)
                                  | (uint32_t)(tile * BN + c);   // 10-bit local col
                    ins6(__uint_as_float(kb), bd[fj]);
                }
            }
        }
    }

    // block merge: 8 lists per row (wy x q) -> 6 packed keys per row per split
    __syncthreads();                       // all frag reads done; reuse smraw
    float* dump = (float*)smraw;           // 128 rows * 8 copies * 6 = 24 KB
#pragma unroll
    for (int fj = 0; fj < 4; ++fj) {
        const int r    = wx * 64 + fj * 16 + pl;
        const int copy = wy * 4 + q;
        float* d = &dump[(size_t)(r * 8 + copy) * 6];
#pragma unroll
        for (int k = 0; k < 6; ++k) d[k] = bd[fj][k];
    }
    __syncthreads();
    if (tid < 128) {
        float md[6];
#pragma unroll
        for (int k = 0; k < 6; ++k) md[k] = 3.0e38f;
        const float* src = &dump[(size_t)tid * 48];
#pragma unroll
        for (int g = 0; g < 48; ++g) ins6(src[g], md);
        float* dst = part + (size_t)(row0 + tid) * 48 + cs * 6;
#pragma unroll
        for (int k = 0; k < 6; ++k) dst[k] = md[k];
    }
}

// K2: merge 8 packed-key lists per row (direct global reads, no LDS),
// compute weights, scatter 6 values.
__global__ __launch_bounds__(256) void final3(const float* __restrict__ part,
                                              float* __restrict__ out) {
    const int r = blockIdx.x * 256 + threadIdx.x;
    const float4* p4 = (const float4*)(part + (size_t)r * 48);
    float4 buf[12];
#pragma unroll
    for (int i = 0; i < 12; ++i) buf[i] = p4[i];
    const float* keys = (const float*)buf;

    float md[6]; int mi[6];
#pragma unroll
    for (int k = 0; k < 6; ++k) { md[k] = 3.0e38f; mi[k] = 0; }
#pragma unroll
    for (int s = 0; s < 8; ++s)
#pragma unroll
        for (int k = 0; k < 6; ++k) {
            uint32_t kb = __float_as_uint(keys[s * 6 + k]);
            float d2 = __uint_as_float(kb & 0xFFFFFC00u);
            int  col = s * CPB2 + (int)(kb & 1023u);
            insert6(d2, col, md, mi);
        }
    const float T = sqrtf(md[5]);
    float wv[6], norm = 0.f;
#pragma unroll
    for (int k = 0; k < 6; ++k) { wv[k] = T - sqrtf(md[k]) + 1e-10f; norm += wv[k]; }
    const float inv = 1.0f / fmaxf(norm, 1e-12f);
    const size_t base = (size_t)r * NPTS;
#pragma unroll
    for (int k = 0; k < 6; ++k) out[base + mi[k]] = wv[k] * inv;
}

// ------------------- fallback fp32 path (round 1, passing) -------------------
#define RB      32
#define CT      64
#define SPLITS  8
#define CPB     (NPTS / SPLITS)
#define NTILES  (CPB / CT)
#define PADS    132

__global__ __launch_bounds__(256) void knn_partial(const float* __restrict__ F,
                                                   float* __restrict__ out) {
    __shared__ float rowF[RB * PADS];
    __shared__ float colF[CT * PADS];
    __shared__ float sqr[RB];
    __shared__ float sqc[CT];

    const int tid  = threadIdx.x;
    const int bx   = blockIdx.x;
    const int rb   = bx & ((NPTS / RB) - 1);
    const int cs   = bx >> 8;
    const int row0 = rb * RB;
    const int col0 = cs * CPB;

#pragma unroll
    for (int m = 0; m < 4; ++m) {
        int flat = m * 256 + tid;
        int r = flat >> 5, kq = flat & 31;
        float4 v = *(const float4*)&F[(size_t)(row0 + r) * DIM + kq * 4];
        *(float4*)&rowF[r * PADS + kq * 4] = v;
    }
    __syncthreads();
    if (tid < RB) {
        float s = 0.f;
#pragma unroll
        for (int kq = 0; kq < 32; ++kq) {
            float4 v = *(const float4*)&rowF[tid * PADS + kq * 4];
            s += v.x * v.x + v.y * v.y + v.z * v.z + v.w * v.w;
        }
        sqr[tid] = s;
    }

    const int rl = tid >> 4;
    const int cl = tid & 15;

    float bd[2][6];
    int   bi[2][6];
#pragma unroll
    for (int i = 0; i < 2; ++i)
#pragma unroll
        for (int k = 0; k < 6; ++k) { bd[i][k] = 3.0e38f; bi[i][k] = 0; }

    for (int t = 0; t < NTILES; ++t) {
        const int cbase = col0 + t * CT;
        __syncthreads();
#pragma unroll
        for (int m = 0; m < 8; ++m) {
            int flat = m * 256 + tid;
            int c = flat >> 5, kq = flat & 31;
            float4 v = *(const float4*)&F[(size_t)(cbase + c) * DIM + kq * 4];
            *(float4*)&colF[c * PADS + kq * 4] = v;
        }
        __syncthreads();
        if (tid < CT) {
            float s = 0.f;
#pragma unroll
            for (int kq = 0; kq < 32; ++kq) {
                float4 v = *(const float4*)&colF[tid * PADS + kq * 4];
                s += v.x * v.x + v.y * v.y + v.z * v.z + v.w * v.w;
            }
            sqc[tid] = s;
        }
        __syncthreads();

        float acc[2][4];
#pragma unroll
        for (int i = 0; i < 2; ++i)
#pragma unroll
            for (int j = 0; j < 4; ++j) acc[i][j] = 0.f;

#pragma unroll 4
        for (int kq = 0; kq < 32; ++kq) {
            float4 a[2], b[4];
#pragma unroll
            for (int i = 0; i < 2; ++i)
                a[i] = *(const float4*)&rowF[(rl + 16 * i) * PADS + kq * 4];
#pragma unroll
            for (int j = 0; j < 4; ++j)
                b[j] = *(const float4*)&colF[(cl + 16 * j) * PADS + kq * 4];
#pragma unroll
            for (int i = 0; i < 2; ++i)
#pragma unroll
                for (int j = 0; j < 4; ++j) {
                    acc[i][j] = fmaf(a[i].x, b[j].x, acc[i][j]);
                    acc[i][j] = fmaf(a[i].y, b[j].y, acc[i][j]);
                    acc[i][j] = fmaf(a[i].z, b[j].z, acc[i][j]);
                    acc[i][j] = fmaf(a[i].w, b[j].w, acc[i][j]);
                }
        }

#pragma unroll
        for (int i = 0; i < 2; ++i) {
            const int r = rl + 16 * i;
            const int gr = row0 + r;
#pragma unroll
            for (int j = 0; j < 4; ++j) {
                const int c = cl + 16 * j;
                const int gc = cbase + c;
                float d2 = sqr[r] + sqc[c] - 2.0f * acc[i][j];
                d2 = (gr == gc) ? 1e-30f : fmaxf(d2, 1e-30f);
                insert6(d2, gc, bd[i], bi[i]);
            }
        }
    }

    __syncthreads();
    float* cd = colF;
    float* ci = rowF;
#pragma unroll
    for (int i = 0; i < 2; ++i) {
        const int r = rl + 16 * i;
#pragma unroll
        for (int k = 0; k < 6; ++k) {
            cd[(r * 16 + cl) * 6 + k] = bd[i][k];
            ci[(r * 16 + cl) * 6 + k] = __int_as_float(bi[i][k]);
        }
    }
    __syncthreads();
    if (tid < RB) {
        float md[6]; int mi[6];
#pragma unroll
        for (int k = 0; k < 6; ++k) { md[k] = 3.0e38f; mi[k] = 0; }
        for (int g = 0; g < 16; ++g) {
#pragma unroll
            for (int k = 0; k < 6; ++k)
                insert6(cd[(tid * 16 + g) * 6 + k],
                        __float_as_int(ci[(tid * 16 + g) * 6 + k]), md, mi);
        }
        float* dst = &out[(size_t)(row0 + tid) * NPTS + cs * 12];
#pragma unroll
        for (int k = 0; k < 6; ++k) {
            dst[k] = md[k];
            dst[6 + k] = __int_as_float(mi[k]);
        }
    }
}

__global__ __launch_bounds__(256) void knn_finalize(float* __restrict__ out) {
    __shared__ float pbuf[SPLITS * 12];
    __shared__ float w_s[6];
    __shared__ int   wi_s[6];

    const int    tid  = threadIdx.x;
    const size_t base = (size_t)blockIdx.x * NPTS;

    if (tid < SPLITS * 12) pbuf[tid] = out[base + tid];
    __syncthreads();

    if (tid == 0) {
        float md[6]; int mi[6];
#pragma unroll
        for (int k = 0; k < 6; ++k) { md[k] = 3.0e38f; mi[k] = 0; }
        for (int s = 0; s < SPLITS; ++s)
#pragma unroll
            for (int k = 0; k < 6; ++k)
                insert6(pbuf[s * 12 + k], __float_as_int(pbuf[s * 12 + 6 + k]), md, mi);
        const float T = sqrtf(md[5]);
        float w[6]; float norm = 0.f;
#pragma unroll
        for (int k = 0; k < 6; ++k) { w[k] = T - sqrtf(md[k]) + 1e-10f; norm += w[k]; }
        const float inv = 1.0f / fmaxf(norm, 1e-12f);
#pragma unroll
        for (int k = 0; k < 6; ++k) { w_s[k] = w[k] * inv; wi_s[k] = mi[k]; }
    }
    __syncthreads();

#pragma unroll
    for (int m = 0; m < 8; ++m)
        *(float4*)&out[base + (size_t)(m * 256 + tid) * 4] = make_float4(0.f, 0.f, 0.f, 0.f);
    __syncthreads();

    if (tid < 6) out[base + wi_s[tid]] = w_s[tid];
}

extern "C" void kernel_launch(void* const* d_in, const int* in_sizes, int n_in,
                              void* d_out, int out_size, void* d_ws, size_t ws_size,
                              hipStream_t stream) {
    const float* F   = (const float*)d_in[0];
    float*       out = (float*)d_out;
    if (ws_size >= WS_NEED) {
        short* Hi  = (short*)((char*)d_ws + WS_HI);
        short* Lo  = (short*)((char*)d_ws + WS_LO);
        float* sqp = (float*)((char*)d_ws + WS_SQ);
        float* prt = (float*)((char*)d_ws + WS_PART);
        prep2<<<dim3(NPTS * DIM / 256), dim3(256), 0, stream>>>(F, Hi, Lo, sqp);
        knn_mfma3<<<dim3(64 * NSPLIT), dim3(256), 0, stream>>>(Hi, Lo, sqp, prt, out);
        final3<<<dim3(NPTS / 256), dim3(256), 0, stream>>>(prt, out);
    } else {
        knn_partial<<<dim3((NPTS / RB) * SPLITS), dim3(256), 0, stream>>>(F, out);
        knn_finalize<<<dim3(NPTS), dim3(256), 0, stream>>>(out);
    }
}

// Round 10
// 299.148 us; speedup vs baseline: 2.3632x; 1.0414x over previous
//
#include <hip/hip_runtime.h>
#include <cstddef>
#include <cstdint>

#define NPTS 8192
#define DIM  128

// MFMA path: 128x128 tiles, K3=256 split-bf16 (A'=[hi|lo] . B'=[hi|hi], i.e.
// (hiA+loA).hiB — drops the hiA.loB term; error ~0.025 RMS on d^2, well under
// the 2e-2 weight gate). BK=64 per staged step, double-buffered LDS, 1 barrier
// per step, packed-key top-6, zero-fill interleaved (4 f32x4/thread/step,
// REGULAR stores: ack at L2, not HBM, so the next barrier's vmcnt(0) drain
// is cheap — nt stores were the suspected ~10us/kernel drain exposure).
#define K3      256
#define BK      64
#define KITERS  (K3 / BK)        // 4
#define BM      128
#define BN      128
#define NSPLIT  8
#define CPB2    (NPTS / NSPLIT)  // 1024
#define NT2     (CPB2 / BN)      // 8

using bf16x8 = __attribute__((ext_vector_type(8))) short;
using f32x4  = __attribute__((ext_vector_type(4))) float;

// ws layout (bytes): Hi | Lo | sq | part (8192 rows x 8 splits x 6 packed keys)
#define WS_HI   ((size_t)0)
#define WS_LO   ((size_t)NPTS * DIM * 2)            // 2 MB
#define WS_SQ   ((size_t)2 * NPTS * DIM * 2)        // 4 MB
#define WS_PART (WS_SQ + (size_t)NPTS * 4)          // +32 KB
#define WS_NEED (WS_PART + (size_t)NPTS * 48 * 4)   // ~5.7 MB

// branchless sorted-ascending insert of packed key (positive floats only)
__device__ __forceinline__ void ins6(float t, float bd[6]) {
#pragma unroll
    for (int q = 0; q < 6; ++q) {
        float lo = fminf(bd[q], t);
        t        = fmaxf(bd[q], t);
        bd[q]    = lo;
    }
}

// classic (d2, idx) insert for the small final merge
__device__ __forceinline__ void insert6(float d, int idx, float bd[6], int bi[6]) {
    if (d < bd[5]) {
        bd[5] = d; bi[5] = idx;
#pragma unroll
        for (int q = 5; q >= 1; --q) {
            if (bd[q] < bd[q - 1]) {
                float td = bd[q]; bd[q] = bd[q - 1]; bd[q - 1] = td;
                int   ti = bi[q]; bi[q] = bi[q - 1]; bi[q - 1] = ti;
            }
        }
    }
}

__device__ __forceinline__ void async16(const void* g, void* l) {
    __builtin_amdgcn_global_load_lds(
        (const __attribute__((address_space(1))) void*)g,
        (__attribute__((address_space(3))) void*)l,
        16, 0, 0);
}

// K0: elementwise fp32 -> (hi, lo) bf16 planes + per-row |f|^2 via shfl reduce.
__global__ __launch_bounds__(256) void prep2(const float* __restrict__ F,
                                             short* __restrict__ Hi,
                                             short* __restrict__ Lo,
                                             float* __restrict__ sq) {
    __shared__ float wsum[4];
    const int tid = threadIdx.x;
    const int idx = blockIdx.x * 256 + tid;
    float f = F[idx];
    uint32_t u  = __float_as_uint(f);
    uint32_t hb = (u + 0x7fffu + ((u >> 16) & 1u)) >> 16;     // RNE to bf16
    float hf = __uint_as_float(hb << 16);
    float lo = f - hf;
    uint32_t ul = __float_as_uint(lo);
    uint32_t lb = (ul + 0x7fffu + ((ul >> 16) & 1u)) >> 16;
    float lf = __uint_as_float(lb << 16);
    Hi[idx] = (short)hb;
    Lo[idx] = (short)lb;
    float fh = hf + lf;          // the value the GEMM's A-side sees
    float s  = fh * fh;
#pragma unroll
    for (int m = 32; m >= 1; m >>= 1) s += __shfl_xor(s, m, 64);
    if ((tid & 63) == 0) wsum[tid >> 6] = s;
    __syncthreads();
    if (tid < 2) sq[blockIdx.x * 2 + tid] = wsum[tid * 2] + wsum[tid * 2 + 1];
}

// K1: swapped-operand MFMA distance + packed-key top-6 + interleaved zero-fill.
__global__ __launch_bounds__(256, 2) void knn_mfma3(const short* __restrict__ Hi,
                                                    const short* __restrict__ Lo,
                                                    const float* __restrict__ sq,
                                                    float* __restrict__ part,
                                                    float* __restrict__ out) {
    __shared__ __align__(16) char smraw[65536];   // 2 x (16KB A | 16KB B); dump reuses 24KB

    const int tid  = threadIdx.x;
    const int lane = tid & 63;
    const int w    = tid >> 6;        // wave 0..3
    const int wy   = w >> 1;          // col half
    const int wx   = w & 1;           // row half
    const int q    = lane >> 4;       // quad 0..3
    const int pl   = lane & 15;

    const int bx   = blockIdx.x;
    const int rb   = bx & 63;
    const int cs   = bx >> 6;
    const int row0 = rb * BM;
    const int col0 = cs * CPB2;

    // staging decode: slot = w*256 + i*64 + lane -> (point, logical chunk)
    int pS[4], cS[4];
#pragma unroll
    for (int i = 0; i < 4; ++i) {
        int ch = w * 256 + i * 64 + lane;
        pS[i] = ch >> 3;
        cS[i] = (ch & 7) ^ (pS[i] & 7);
    }

    // frag LDS byte offsets: phys chunk = point*8 + (kchunk ^ (point&7))
    int colOff[4][2], rowOff[4][2];
#pragma unroll
    for (int f = 0; f < 4; ++f) {
#pragma unroll
        for (int s = 0; s < 2; ++s) {
            int pc = wy * 64 + f * 16 + pl;
            int cc = (s * 4 + q) ^ (pc & 7);
            colOff[f][s] = (pc * 64 + cc * 8) * 2;
            int pr = wx * 64 + f * 16 + pl;
            int cr = (s * 4 + q) ^ (pr & 7);
            rowOff[f][s] = (pr * 64 + cr * 8) * 2;
        }
    }

    float sqr4[4];
#pragma unroll
    for (int fj = 0; fj < 4; ++fj) sqr4[fj] = sq[row0 + wx * 64 + fj * 16 + pl];

    // packed-key top-6 per owned row (4 rows per thread)
    float bd[4][6];
#pragma unroll
    for (int fj = 0; fj < 4; ++fj)
#pragma unroll
        for (int k = 0; k < 6; ++k) bd[fj][k] = 3.0e38f;

    auto stage = [&](int b, int nt, int nk) {
        const short* plA = (nk >= 2) ? Lo : Hi;     // A sections: hi, lo
        const short* plB = Hi;                      // B sections: hi, hi
        const int half = (nk & 1) * 64;
        const int tcn  = col0 + nt * BN;
        char* baseA = smraw + b * 32768;
        char* baseB = baseA + 16384;
#pragma unroll
        for (int i = 0; i < 4; ++i) {
            const short* gA = plA + (size_t)(row0 + pS[i]) * DIM + half + cS[i] * 8;
            async16(gA, baseA + (w * 256 + i * 64) * 16);
            const short* gB = plB + (size_t)(tcn + pS[i]) * DIM + half + cS[i] * 8;
            async16(gB, baseB + (w * 256 + i * 64) * 16);
        }
    };

    stage(0, 0, 0);
    int sidx = 0;

    const f32x4 z4 = {0.f, 0.f, 0.f, 0.f};

    for (int tile = 0; tile < NT2; ++tile) {
        const int tc0 = col0 + tile * BN;

        f32x4 acc[4][4];
#pragma unroll
        for (int fi = 0; fi < 4; ++fi)
#pragma unroll
            for (int fj = 0; fj < 4; ++fj) acc[fi][fj] = 0.0f;

        for (int kk = 0; kk < KITERS; ++kk) {
            const int b = sidx & 1;
            __syncthreads();
            int nk = kk + 1, nt = tile;
            if (nk == KITERS) { nk = 0; nt = tile + 1; }
            if (nt < NT2) stage(b ^ 1, nt, nk);

            // interleaved zero-fill quota: 4 f32x4/thread/step (regular stores:
            // L2 ack drains cheaply at the next barrier; writeback is async).
            // 32 steps x 1024 f32x4 = 32768 = the full 128x1024 region.
            {
                int base = sidx * 1024 + tid;
#pragma unroll
                for (int it = 0; it < 4; ++it) {
                    int flat = base + it * 256;
                    int r  = flat >> 8;           // 0..127
                    int c4 = (flat & 255) * 4;    // 0..1020
                    *(f32x4*)&out[(size_t)(row0 + r) * NPTS + col0 + c4] = z4;
                }
            }

            char* baseA = smraw + b * 32768;
            char* baseB = baseA + 16384;
#pragma unroll
            for (int s = 0; s < 2; ++s) {
                bf16x8 cf[4], rf[4];
#pragma unroll
                for (int fi = 0; fi < 4; ++fi)
                    cf[fi] = *(const bf16x8*)(baseB + colOff[fi][s]);
#pragma unroll
                for (int fj = 0; fj < 4; ++fj)
                    rf[fj] = *(const bf16x8*)(baseA + rowOff[fj][s]);
#pragma unroll
                for (int fi = 0; fi < 4; ++fi)
#pragma unroll
                    for (int fj = 0; fj < 4; ++fj)
                        acc[fi][fj] = __builtin_amdgcn_mfma_f32_16x16x32_bf16(
                            cf[fi], rf[fj], acc[fi][fj], 0, 0, 0);
            }
            ++sidx;
        }

        // in-register epilogue: rows r = wx*64+fj*16+pl, cols c = wy*64+fi*16+q*4+reg
        const bool diag = (tc0 == row0);
        float4 sqc4[4];
#pragma unroll
        for (int fi = 0; fi < 4; ++fi)
            sqc4[fi] = *(const float4*)&sq[tc0 + wy * 64 + fi * 16 + q * 4];

#pragma unroll
        for (int fj = 0; fj < 4; ++fj) {
            const float sr = sqr4[fj];
            const int   r  = wx * 64 + fj * 16 + pl;
#pragma unroll
            for (int fi = 0; fi < 4; ++fi) {
                const float* sc = (const float*)&sqc4[fi];
#pragma unroll
                for (int reg = 0; reg < 4; ++reg) {
                    const int c = wy * 64 + fi * 16 + q * 4 + reg;
                    float d2 = fmaf(-2.0f, acc[fi][fj][reg], sr + sc[reg]);
                    d2 = fmaxf(d2, 1e-30f);
                    if (diag && r == c) d2 = 1e-30f;    // self-distance
                    uint32_t kb = (__float_as_uint(d2) & 0xFFFFFC00u)
                                  | (uint32_t)(tile * BN + c);   // 10-bit local col
                    ins6(__uint_as_float(kb), bd[fj]);
                }
            }
        }
    }

    // block merge: 8 lists per row (wy x q) -> 6 packed keys per row per split
    __syncthreads();                       // all frag reads done; reuse smraw
    float* dump = (float*)smraw;           // 128 rows * 8 copies * 6 = 24 KB
#pragma unroll
    for (int fj = 0; fj < 4; ++fj) {
        const int r    = wx * 64 + fj * 16 + pl;
        const int copy = wy * 4 + q;
        float* d = &dump[(size_t)(r * 8 + copy) * 6];
#pragma unroll
        for (int k = 0; k < 6; ++k) d[k] = bd[fj][k];
    }
    __syncthreads();
    if (tid < 128) {
        float md[6];
#pragma unroll
        for (int k = 0; k < 6; ++k) md[k] = 3.0e38f;
        const float* src = &dump[(size_t)tid * 48];
#pragma unroll
        for (int g = 0; g < 48; ++g) ins6(src[g], md);
        float* dst = part + (size_t)(row0 + tid) * 48 + cs * 6;
#pragma unroll
        for (int k = 0; k < 6; ++k) dst[k] = md[k];
    }
}

// K2: merge 8 packed-key lists per row (direct global reads, no LDS),
// compute weights, scatter 6 values.
__global__ __launch_bounds__(256) void final3(const float* __restrict__ part,
                                              float* __restrict__ out) {
    const int r = blockIdx.x * 256 + threadIdx.x;
    const float4* p4 = (const float4*)(part + (size_t)r * 48);
    float4 buf[12];
#pragma unroll
    for (int i = 0; i < 12; ++i) buf[i] = p4[i];
    const float* keys = (const float*)buf;

    float md[6]; int mi[6];
#pragma unroll
    for (int k = 0; k < 6; ++k) { md[k] = 3.0e38f; mi[k] = 0; }
#pragma unroll
    for (int s = 0; s < 8; ++s)
#pragma unroll
        for (int k = 0; k < 6; ++k) {
            uint32_t kb = __float_as_uint(keys[s * 6 + k]);
            float d2 = __uint_as_float(kb & 0xFFFFFC00u);
            int  col = s * CPB2 + (int)(kb & 1023u);
            insert6(d2, col, md, mi);
        }
    const float T = sqrtf(md[5]);
    float wv[6], norm = 0.f;
#pragma unroll
    for (int k = 0; k < 6; ++k) { wv[k] = T - sqrtf(md[k]) + 1e-10f; norm += wv[k]; }
    const float inv = 1.0f / fmaxf(norm, 1e-12f);
    const size_t base = (size_t)r * NPTS;
#pragma unroll
    for (int k = 0; k < 6; ++k) out[base + mi[k]] = wv[k] * inv;
}

// ------------------- fallback fp32 path (round 1, passing) -------------------
#define RB      32
#define CT      64
#define SPLITS  8
#define CPB     (NPTS / SPLITS)
#define NTILES  (CPB / CT)
#define PADS    132

__global__ __launch_bounds__(256) void knn_partial(const float* __restrict__ F,
                                                   float* __restrict__ out) {
    __shared__ float rowF[RB * PADS];
    __shared__ float colF[CT * PADS];
    __shared__ float sqr[RB];
    __shared__ float sqc[CT];

    const int tid  = threadIdx.x;
    const int bx   = blockIdx.x;
    const int rb   = bx & ((NPTS / RB) - 1);
    const int cs   = bx >> 8;
    const int row0 = rb * RB;
    const int col0 = cs * CPB;

#pragma unroll
    for (int m = 0; m < 4; ++m) {
        int flat = m * 256 + tid;
        int r = flat >> 5, kq = flat & 31;
        float4 v = *(const float4*)&F[(size_t)(row0 + r) * DIM + kq * 4];
        *(float4*)&rowF[r * PADS + kq * 4] = v;
    }
    __syncthreads();
    if (tid < RB) {
        float s = 0.f;
#pragma unroll
        for (int kq = 0; kq < 32; ++kq) {
            float4 v = *(const float4*)&rowF[tid * PADS + kq * 4];
            s += v.x * v.x + v.y * v.y + v.z * v.z + v.w * v.w;
        }
        sqr[tid] = s;
    }

    const int rl = tid >> 4;
    const int cl = tid & 15;

    float bd[2][6];
    int   bi[2][6];
#pragma unroll
    for (int i = 0; i < 2; ++i)
#pragma unroll
        for (int k = 0; k < 6; ++k) { bd[i][k] = 3.0e38f; bi[i][k] = 0; }

    for (int t = 0; t < NTILES; ++t) {
        const int cbase = col0 + t * CT;
        __syncthreads();
#pragma unroll
        for (int m = 0; m < 8; ++m) {
            int flat = m * 256 + tid;
            int c = flat >> 5, kq = flat & 31;
            float4 v = *(const float4*)&F[(size_t)(cbase + c) * DIM + kq * 4];
            *(float4*)&colF[c * PADS + kq * 4] = v;
        }
        __syncthreads();
        if (tid < CT) {
            float s = 0.f;
#pragma unroll
            for (int kq = 0; kq < 32; ++kq) {
                float4 v = *(const float4*)&colF[tid * PADS + kq * 4];
                s += v.x * v.x + v.y * v.y + v.z * v.z + v.w * v.w;
            }
            sqc[tid] = s;
        }
        __syncthreads();

        float acc[2][4];
#pragma unroll
        for (int i = 0; i < 2; ++i)
#pragma unroll
            for (int j = 0; j < 4; ++j) acc[i][j] = 0.f;

#pragma unroll 4
        for (int kq = 0; kq < 32; ++kq) {
            float4 a[2], b[4];
#pragma unroll
            for (int i = 0; i < 2; ++i)
                a[i] = *(const float4*)&rowF[(rl + 16 * i) * PADS + kq * 4];
#pragma unroll
            for (int j = 0; j < 4; ++j)
                b[j] = *(const float4*)&colF[(cl + 16 * j) * PADS + kq * 4];
#pragma unroll
            for (int i = 0; i < 2; ++i)
#pragma unroll
                for (int j = 0; j < 4; ++j) {
                    acc[i][j] = fmaf(a[i].x, b[j].x, acc[i][j]);
                    acc[i][j] = fmaf(a[i].y, b[j].y, acc[i][j]);
                    acc[i][j] = fmaf(a[i].z, b[j].z, acc[i][j]);
                    acc[i][j] = fmaf(a[i].w, b[j].w, acc[i][j]);
                }
        }

#pragma unroll
        for (int i = 0; i < 2; ++i) {
            const int r = rl + 16 * i;
            const int gr = row0 + r;
#pragma unroll
            for (int j = 0; j < 4; ++j) {
                const int c = cl + 16 * j;
                const int gc = cbase + c;
                float d2 = sqr[r] + sqc[c] - 2.0f * acc[i][j];
                d2 = (gr == gc) ? 1e-30f : fmaxf(d2, 1e-30f);
                insert6(d2, gc, bd[i], bi[i]);
            }
        }
    }

    __syncthreads();
    float* cd = colF;
    float* ci = rowF;
#pragma unroll
    for (int i = 0; i < 2; ++i) {
        const int r = rl + 16 * i;
#pragma unroll
        for (int k = 0; k < 6; ++k) {
            cd[(r * 16 + cl) * 6 + k] = bd[i][k];
            ci[(r * 16 + cl) * 6 + k] = __int_as_float(bi[i][k]);
        }
    }
    __syncthreads();
    if (tid < RB) {
        float md[6]; int mi[6];
#pragma unroll
        for (int k = 0; k < 6; ++k) { md[k] = 3.0e38f; mi[k] = 0; }
        for (int g = 0; g < 16; ++g) {
#pragma unroll
            for (int k = 0; k < 6; ++k)
                insert6(cd[(tid * 16 + g) * 6 + k],
                        __float_as_int(ci[(tid * 16 + g) * 6 + k]), md, mi);
        }
        float* dst = &out[(size_t)(row0 + tid) * NPTS + cs * 12];
#pragma unroll
        for (int k = 0; k < 6; ++k) {
            dst[k] = md[k];
            dst[6 + k] = __int_as_float(mi[k]);
        }
    }
}

__global__ __launch_bounds__(256) void knn_finalize(float* __restrict__ out) {
    __shared__ float pbuf[SPLITS * 12];
    __shared__ float w_s[6];
    __shared__ int   wi_s[6];

    const int    tid  = threadIdx.x;
    const size_t base = (size_t)blockIdx.x * NPTS;

    if (tid < SPLITS * 12) pbuf[tid] = out[base + tid];
    __syncthreads();

    if (tid == 0) {
        float md[6]; int mi[6];
#pragma unroll
        for (int k = 0; k < 6; ++k) { md[k] = 3.0e38f; mi[k] = 0; }
        for (int s = 0; s < SPLITS; ++s)
#pragma unroll
            for (int k = 0; k < 6; ++k)
                insert6(pbuf[s * 12 + k], __float_as_int(pbuf[s * 12 + 6 + k]), md, mi);
        const float T = sqrtf(md[5]);
        float w[6]; float norm = 0.f;
#pragma unroll
        for (int k = 0; k < 6; ++k) { w[k] = T - sqrtf(md[k]) + 1e-10f; norm += w[k]; }
        const float inv = 1.0f / fmaxf(norm, 1e-12f);
#pragma unroll
        for (int k = 0; k < 6; ++k) { w_s[k] = w[k] * inv; wi_s[k] = mi[k]; }
    }
    __syncthreads();

#pragma unroll
    for (int m = 0; m < 8; ++m)
        *(float4*)&out[base + (size_t)(m * 256 + tid) * 4] = make_float4(0.f, 0.f, 0.f, 0.f);
    __syncthreads();

    if (tid < 6) out[base + wi_s[tid]] = w_s[tid];
}

extern "C" void kernel_launch(void* const* d_in, const int* in_sizes, int n_in,
                              void* d_out, int out_size, void* d_ws, size_t ws_size,
                              hipStream_t stream) {
    const float* F   = (const float*)d_in[0];
    float*       out = (float*)d_out;
    if (ws_size >= WS_NEED) {
        short* Hi  = (short*)((char*)d_ws + WS_HI);
        short* Lo  = (short*)((char*)d_ws + WS_LO);
        float* sqp = (float*)((char*)d_ws + WS_SQ);
        float* prt = (float*)((char*)d_ws + WS_PART);
        prep2<<<dim3(NPTS * DIM / 256), dim3(256), 0, stream>>>(F, Hi, Lo, sqp);
        knn_mfma3<<<dim3(64 * NSPLIT), dim3(256), 0, stream>>>(Hi, Lo, sqp, prt, out);
        final3<<<dim3(NPTS / 256), dim3(256), 0, stream>>>(prt, out);
    } else {
        knn_partial<<<dim3((NPTS / RB) * SPLITS), dim3(256), 0, stream>>>(F, out);
        knn_finalize<<<dim3(NPTS), dim3(256), 0, stream>>>(out);
    }
}